// Round 5
// baseline (957.085 us; speedup 1.0000x reference)
//
#include <hip/hip_runtime.h>
#include <hip/hip_bf16.h>

// ---------------------------------------------------------------------------
// GAT encoder: 3 GATConv layers, N=100K nodes, E=1.6M edges (+N self loops).
// Pinned dtypes: float inputs = f32, edges = int32 (R2==R3 bitwise proof),
// OUTPUT = f32 (reference output dtype; R2-R4 failed by writing bf16 here).
// All intermediates f32. Inter-layer activations live in d_out (f32 [N,64]).
// Layer 2 via linearity: Agg = sum_e alpha*X2[src]; out = Agg@W2 + b2;
// alpha2 = X2@(W2@a2). CSR grouped by dst built per call; k_edge = one wave
// per dst node (max, sum-exp, weighted aggregation; no atomics).
// ---------------------------------------------------------------------------

#define LRELU(x, a) fmaxf((x), (a) * (x))

// flag: 0 => int64 (all sampled high words zero), 1 => int32
__global__ __launch_bounds__(1024) void k_detect(const int* __restrict__ eraw, int e,
                                                 int* __restrict__ flag) {
    int i = threadIdx.x;
    long long step = (long long)e / 1024;
    if (step == 0) step = 1;
    long long pos = 2LL * (i * step) + 1;
    if (pos < 2LL * e && eraw[pos] != 0) atomicExch(flag, 1);
}

__global__ __launch_bounds__(256) void k_hist(const int* __restrict__ eraw, int e, int etot,
                                              const int* __restrict__ flag,
                                              int* __restrict__ deg) {
    int i = blockIdx.x * blockDim.x + threadIdx.x;
    if (i >= etot) return;
    int d;
    if (i < e) d = (*flag == 0) ? eraw[2 * (e + i)] : eraw[e + i];
    else d = i - e;
    atomicAdd(&deg[d], 1);
}

__global__ __launch_bounds__(1024) void k_scan1(const int* __restrict__ deg,
                                                int* __restrict__ rowstart,
                                                int* __restrict__ bsums, int n) {
    __shared__ int sm[1024];
    int i = blockIdx.x * 1024 + threadIdx.x;
    int v = (i < n) ? deg[i] : 0;
    sm[threadIdx.x] = v;
    __syncthreads();
    for (int o = 1; o < 1024; o <<= 1) {
        int t = (threadIdx.x >= o) ? sm[threadIdx.x - o] : 0;
        __syncthreads();
        sm[threadIdx.x] += t;
        __syncthreads();
    }
    if (i < n) rowstart[i] = sm[threadIdx.x] - v;  // exclusive
    if (threadIdx.x == 1023) bsums[blockIdx.x] = sm[1023];
}

__global__ __launch_bounds__(1024) void k_scan2(int* __restrict__ bsums, int nb) {
    __shared__ int sm[1024];
    int v = (threadIdx.x < nb) ? bsums[threadIdx.x] : 0;
    sm[threadIdx.x] = v;
    __syncthreads();
    for (int o = 1; o < 1024; o <<= 1) {
        int t = (threadIdx.x >= o) ? sm[threadIdx.x - o] : 0;
        __syncthreads();
        sm[threadIdx.x] += t;
        __syncthreads();
    }
    if (threadIdx.x < nb) bsums[threadIdx.x] = sm[threadIdx.x] - v;  // exclusive
}

__global__ __launch_bounds__(256) void k_scan3(int* __restrict__ rowstart,
                                               const int* __restrict__ bsums, int n, int etot) {
    int i = blockIdx.x * blockDim.x + threadIdx.x;
    if (i < n) rowstart[i] += bsums[i >> 10];
    if (i == 0) rowstart[n] = etot;
}

__global__ __launch_bounds__(256) void k_scatter(const int* __restrict__ eraw, int e, int etot,
                                                 const int* __restrict__ flag,
                                                 const int* __restrict__ rowstart,
                                                 int* __restrict__ cursor, int* __restrict__ csr) {
    int i = blockIdx.x * blockDim.x + threadIdx.x;
    if (i >= etot) return;
    int s, d;
    if (i < e) {
        if (*flag == 0) { s = eraw[2 * i]; d = eraw[2 * (e + i)]; }
        else            { s = eraw[i];     d = eraw[e + i]; }
    } else {
        s = i - e; d = i - e;
    }
    int pos = rowstart[d] + atomicAdd(&cursor[d], 1);
    csr[pos] = s;
}

// va = W2 @ as2, vd = W2 @ ad2  (W2 [64,64] row-major, as2/ad2 [64])
__global__ __launch_bounds__(64) void k_prep(const float* __restrict__ W2,
                                             const float* __restrict__ as2,
                                             const float* __restrict__ ad2,
                                             float* __restrict__ va, float* __restrict__ vd) {
    int k = threadIdx.x;
    float sa = 0.f, sd = 0.f;
    for (int j = 0; j < 64; j++) {
        float w = W2[k * 64 + j];
        sa += w * as2[j];
        sd += w * ad2[j];
    }
    va[k] = sa;
    vd[k] = sd;
}

// layer 0: h = x[N,2] @ W[2,64]; per-head (4x16) alpha dots. One wave per node.
__global__ __launch_bounds__(256) void k_feat0(const float* __restrict__ Xin,
                                               const float* __restrict__ W,
                                               const float* __restrict__ Asrc,
                                               const float* __restrict__ Adst,
                                               float* __restrict__ H, float* __restrict__ asn,
                                               float* __restrict__ adn, int n) {
    const int wv = threadIdx.x >> 6, ln = threadIdx.x & 63;
    const float w0 = W[ln], w1 = W[64 + ln];
    const float a_s = Asrc[ln], a_d = Adst[ln];
    for (int node = blockIdx.x * 4 + wv; node < n; node += gridDim.x * 4) {
        float x0 = Xin[node * 2 + 0], x1 = Xin[node * 2 + 1];
        float acc = fmaf(x1, w1, x0 * w0);
        float ts = acc * a_s, td = acc * a_d;
        #pragma unroll
        for (int o = 1; o < 16; o <<= 1) {
            ts += __shfl_xor(ts, o, 16);
            td += __shfl_xor(td, o, 16);
        }
        H[node * 64 + ln] = acc;
        if ((ln & 15) == 0) {
            asn[node * 4 + (ln >> 4)] = ts;
            adn[node * 4 + (ln >> 4)] = td;
        }
    }
}

// layers 1: h = X[N,64] @ W[64,64]; per-head alpha dots. Row broadcast via __shfl.
__global__ __launch_bounds__(256) void k_feat64(const float* __restrict__ Xin,
                                                const float* __restrict__ W,
                                                const float* __restrict__ Asrc,
                                                const float* __restrict__ Adst,
                                                float* __restrict__ H, float* __restrict__ asn,
                                                float* __restrict__ adn, int n) {
    __shared__ float Ws[64 * 64];
    for (int i = threadIdx.x; i < 64 * 64; i += 256) Ws[i] = W[i];
    __syncthreads();
    const int wv = threadIdx.x >> 6, ln = threadIdx.x & 63;
    const float a_s = Asrc[ln], a_d = Adst[ln];
    for (int node = blockIdx.x * 4 + wv; node < n; node += gridDim.x * 4) {
        float xv = Xin[node * 64 + ln];
        float acc = 0.f;
        #pragma unroll
        for (int k = 0; k < 64; k++) acc = fmaf(__shfl(xv, k), Ws[k * 64 + ln], acc);
        float ts = acc * a_s, td = acc * a_d;
        #pragma unroll
        for (int o = 1; o < 16; o <<= 1) {
            ts += __shfl_xor(ts, o, 16);
            td += __shfl_xor(td, o, 16);
        }
        H[node * 64 + ln] = acc;
        if ((ln & 15) == 0) {
            asn[node * 4 + (ln >> 4)] = ts;
            adn[node * 4 + (ln >> 4)] = td;
        }
    }
}

// layer 2 alpha dots: asn[node] = X2row . va, adn[node] = X2row . vd
__global__ __launch_bounds__(256) void k_alpha2(const float* __restrict__ Xin,
                                                const float* __restrict__ va,
                                                const float* __restrict__ vd,
                                                float* __restrict__ asn, float* __restrict__ adn,
                                                int n) {
    const int wv = threadIdx.x >> 6, ln = threadIdx.x & 63;
    const float a_s = va[ln], a_d = vd[ln];
    for (int node = blockIdx.x * 4 + wv; node < n; node += gridDim.x * 4) {
        float xv = Xin[node * 64 + ln];
        float ts = xv * a_s, td = xv * a_d;
        #pragma unroll
        for (int o = 1; o < 64; o <<= 1) {
            ts += __shfl_xor(ts, o);
            td += __shfl_xor(td, o);
        }
        if (ln == 0) { asn[node] = ts; adn[node] = td; }
    }
}

// One wave per dst node: segment softmax (max, sum-exp) + weighted aggregation.
// FINAL=false: Out = leaky(acc + bias, 0.01)  (inter-layer activation)
// FINAL=true : Out = acc                      (layer-2 X-aggregation)
template <int HEADS, bool FINAL>
__global__ __launch_bounds__(256) void k_edge(const float* __restrict__ H,
                                              const float* __restrict__ asn,
                                              const float* __restrict__ adn,
                                              const int* __restrict__ rowstart,
                                              const int* __restrict__ csr,
                                              const float* __restrict__ bias,
                                              float* __restrict__ Out, int n) {
    const int wv = threadIdx.x >> 6, ln = threadIdx.x & 63;
    const int node = blockIdx.x * 4 + wv;
    if (node >= n) return;
    constexpr int C = 64 / HEADS;
    const int h_me = ln / C;
    const int start = rowstart[node], end = rowstart[node + 1];

    float adh[HEADS];
    #pragma unroll
    for (int h = 0; h < HEADS; h++) adh[h] = adn[node * HEADS + h];

    // pass 1: per-head max (lanes stride edges)
    float mh[HEADS];
    #pragma unroll
    for (int h = 0; h < HEADS; h++) mh[h] = -1e30f;
    for (int e = start + ln; e < end; e += 64) {
        int s = csr[e];
        if constexpr (HEADS == 4) {
            float4 av = ((const float4*)asn)[s];
            mh[0] = fmaxf(mh[0], LRELU(av.x + adh[0], 0.2f));
            mh[1] = fmaxf(mh[1], LRELU(av.y + adh[1], 0.2f));
            mh[2] = fmaxf(mh[2], LRELU(av.z + adh[2], 0.2f));
            mh[3] = fmaxf(mh[3], LRELU(av.w + adh[3], 0.2f));
        } else {
            mh[0] = fmaxf(mh[0], LRELU(asn[s] + adh[0], 0.2f));
        }
    }
    #pragma unroll
    for (int h = 0; h < HEADS; h++)
        #pragma unroll
        for (int o = 1; o < 64; o <<= 1) mh[h] = fmaxf(mh[h], __shfl_xor(mh[h], o));

    // pass 2: per-head sum of exp
    float sh[HEADS];
    #pragma unroll
    for (int h = 0; h < HEADS; h++) sh[h] = 0.f;
    for (int e = start + ln; e < end; e += 64) {
        int s = csr[e];
        if constexpr (HEADS == 4) {
            float4 av = ((const float4*)asn)[s];
            sh[0] += __expf(LRELU(av.x + adh[0], 0.2f) - mh[0]);
            sh[1] += __expf(LRELU(av.y + adh[1], 0.2f) - mh[1]);
            sh[2] += __expf(LRELU(av.z + adh[2], 0.2f) - mh[2]);
            sh[3] += __expf(LRELU(av.w + adh[3], 0.2f) - mh[3]);
        } else {
            sh[0] += __expf(LRELU(asn[s] + adh[0], 0.2f) - mh[0]);
        }
    }
    #pragma unroll
    for (int h = 0; h < HEADS; h++)
        #pragma unroll
        for (int o = 1; o < 64; o <<= 1) sh[h] += __shfl_xor(sh[h], o);

    const float winv = 1.0f / sh[h_me];
    const float mme = mh[h_me];
    const float adme = adh[h_me];

    // pass 3: weighted aggregation; lane = channel, wave iterates edges
    float acc = 0.f;
    for (int e = start; e < end; e++) {
        int s = csr[e];  // wave-uniform
        float l = LRELU(asn[s * HEADS + h_me] + adme, 0.2f);
        float w = __expf(l - mme) * winv;
        acc = fmaf(w, H[s * 64 + ln], acc);
    }

    if constexpr (FINAL) {
        Out[node * 64 + ln] = acc;
    } else {
        float res = acc + bias[ln];
        Out[node * 64 + ln] = LRELU(res, 0.01f);
    }
}

// final dense: out = Agg[N,64] @ W2[64,64] + b2 -> f32
__global__ __launch_bounds__(256) void k_out(const float* __restrict__ Agg,
                                             const float* __restrict__ W2,
                                             const float* __restrict__ b2,
                                             float* __restrict__ Out, int n) {
    __shared__ float Ws[64 * 64];
    for (int i = threadIdx.x; i < 64 * 64; i += 256) Ws[i] = W2[i];
    __syncthreads();
    const int wv = threadIdx.x >> 6, ln = threadIdx.x & 63;
    const float bb = b2[ln];
    for (int node = blockIdx.x * 4 + wv; node < n; node += gridDim.x * 4) {
        float av = Agg[node * 64 + ln];
        float acc = 0.f;
        #pragma unroll
        for (int k = 0; k < 64; k++) acc = fmaf(__shfl(av, k), Ws[k * 64 + ln], acc);
        Out[node * 64 + ln] = acc + bb;
    }
}

extern "C" void kernel_launch(void* const* d_in, const int* in_sizes, int n_in, void* d_out,
                              int out_size, void* d_ws, size_t ws_size, hipStream_t stream) {
    const float* x = (const float*)d_in[0];
    const int* eraw = (const int*)d_in[1];
    const float* W0 = (const float*)d_in[2];
    const float* as0 = (const float*)d_in[3];
    const float* ad0 = (const float*)d_in[4];
    const float* b0 = (const float*)d_in[5];
    const float* W1 = (const float*)d_in[6];
    const float* as1 = (const float*)d_in[7];
    const float* ad1 = (const float*)d_in[8];
    const float* b1 = (const float*)d_in[9];
    const float* W2 = (const float*)d_in[10];
    const float* as2 = (const float*)d_in[11];
    const float* ad2 = (const float*)d_in[12];
    const float* b2 = (const float*)d_in[13];

    const int n = in_sizes[0] / 2;   // x [N,2]
    const int e = in_sizes[1] / 2;   // edge_index [2,E]
    const int etot = e + n;

    float* Xact = (float*)d_out;  // inter-layer activations live in d_out (f32 [N,64])

    // ---- workspace carve-up (~37 MB total) ----
    char* wp = (char*)d_ws;
    size_t off = 0;
    auto take = [&](size_t bytes) -> void* {
        void* p = wp + off;
        off = (off + bytes + 255) & ~(size_t)255;
        return p;
    };
    float* Hb     = (float*)take((size_t)n * 64 * 4);  // 25.6 MB (H / layer-2 Agg)
    float* asn    = (float*)take((size_t)n * 4 * 4);   // 1.6 MB
    float* adn    = (float*)take((size_t)n * 4 * 4);   // 1.6 MB
    int* deg      = (int*)take((size_t)2 * n * 4);     // 0.8 MB (deg + cursor)
    int* cursor   = deg + n;
    int* rowstart = (int*)take((size_t)(n + 1) * 4);   // 0.4 MB
    int* bsums    = (int*)take(1024 * 4);
    int* flag     = (int*)take(256);
    float* va     = (float*)take(64 * 4);
    float* vd     = (float*)take(64 * 4);
    int* csr      = (int*)take((size_t)etot * 4);      // 6.8 MB
    (void)ws_size;

    hipMemsetAsync(deg, 0, (size_t)2 * n * 4, stream);
    hipMemsetAsync(flag, 0, 4, stream);

    // ---- edge dtype detect + CSR build (grouped by dst) ----
    const int tb = 256;
    k_detect<<<1, 1024, 0, stream>>>(eraw, e, flag);
    k_hist<<<(etot + tb - 1) / tb, tb, 0, stream>>>(eraw, e, etot, flag, deg);
    const int nb = (n + 1023) / 1024;
    k_scan1<<<nb, 1024, 0, stream>>>(deg, rowstart, bsums, n);
    k_scan2<<<1, 1024, 0, stream>>>(bsums, nb);
    k_scan3<<<(n + tb - 1) / tb, tb, 0, stream>>>(rowstart, bsums, n, etot);
    k_scatter<<<(etot + tb - 1) / tb, tb, 0, stream>>>(eraw, e, etot, flag, rowstart, cursor, csr);
    k_prep<<<1, 64, 0, stream>>>(W2, as2, ad2, va, vd);

    const int gsBlocks = 2048;              // grid-stride kernels
    const int edgeBlocks = (n + 3) / 4;     // exact, 4 waves/block

    // ---- layer 0: 2 -> 4x16 concat, +bias(0), leaky(0.01) -> Xact(d_out) ----
    k_feat0<<<gsBlocks, 256, 0, stream>>>(x, W0, as0, ad0, Hb, asn, adn, n);
    k_edge<4, false><<<edgeBlocks, 256, 0, stream>>>(Hb, asn, adn, rowstart, csr, b0, Xact, n);

    // ---- layer 1: 64 -> 4x16 concat, +bias(0), leaky(0.01) -> Xact(d_out) ----
    k_feat64<<<gsBlocks, 256, 0, stream>>>(Xact, W1, as1, ad1, Hb, asn, adn, n);
    k_edge<4, false><<<edgeBlocks, 256, 0, stream>>>(Hb, asn, adn, rowstart, csr, b1, Xact, n);

    // ---- layer 2 (linearity): alpha2 from X2; aggregate X2 -> Hb; dense + b2 ----
    k_alpha2<<<gsBlocks, 256, 0, stream>>>(Xact, va, vd, asn, adn, n);
    k_edge<1, true><<<edgeBlocks, 256, 0, stream>>>(Xact, asn, adn, rowstart, csr, nullptr, Hb, n);
    k_out<<<gsBlocks, 256, 0, stream>>>(Hb, W2, b2, (float*)d_out, n);
}

// Round 6
// 639.177 us; speedup vs baseline: 1.4974x; 1.4974x over previous
//
#include <hip/hip_runtime.h>
#include <hip/hip_bf16.h>

// ---------------------------------------------------------------------------
// GAT encoder: 3 GATConv layers, N=100K nodes, E=1.6M edges (+N self loops).
// Dtypes pinned: float inputs/outputs = f32, edges = int32 (flag fallback for
// int64 kept). Inter-layer activations live in d_out (f32 [N,64]).
// Round-6 restructure:
//   k_edge: ONE fused sweep (no max-shift: logits are O(5), f32 exp safe;
//           softmax normalized by 1/sum at the end). 4 edges in flight per
//           wave: 16-lane group per edge, lane = float4 of H row.
//   k_feat64/k_out: 4 nodes per wave (16-lane group per node), float4 acc,
//           ds_read_b128 W reads, 4 FMA per shfl broadcast.
// ---------------------------------------------------------------------------

#define LRELU(x, a) fmaxf((x), (a) * (x))

// flag: 0 => int64 (all sampled high words zero), 1 => int32
__global__ __launch_bounds__(1024) void k_detect(const int* __restrict__ eraw, int e,
                                                 int* __restrict__ flag) {
    int i = threadIdx.x;
    long long step = (long long)e / 1024;
    if (step == 0) step = 1;
    long long pos = 2LL * (i * step) + 1;
    if (pos < 2LL * e && eraw[pos] != 0) atomicExch(flag, 1);
}

__global__ __launch_bounds__(256) void k_hist(const int* __restrict__ eraw, int e, int etot,
                                              const int* __restrict__ flag,
                                              int* __restrict__ deg) {
    int i = blockIdx.x * blockDim.x + threadIdx.x;
    if (i >= etot) return;
    int d;
    if (i < e) d = (*flag == 0) ? eraw[2 * (e + i)] : eraw[e + i];
    else d = i - e;
    atomicAdd(&deg[d], 1);
}

__global__ __launch_bounds__(1024) void k_scan1(const int* __restrict__ deg,
                                                int* __restrict__ rowstart,
                                                int* __restrict__ bsums, int n) {
    __shared__ int sm[1024];
    int i = blockIdx.x * 1024 + threadIdx.x;
    int v = (i < n) ? deg[i] : 0;
    sm[threadIdx.x] = v;
    __syncthreads();
    for (int o = 1; o < 1024; o <<= 1) {
        int t = (threadIdx.x >= o) ? sm[threadIdx.x - o] : 0;
        __syncthreads();
        sm[threadIdx.x] += t;
        __syncthreads();
    }
    if (i < n) rowstart[i] = sm[threadIdx.x] - v;  // exclusive
    if (threadIdx.x == 1023) bsums[blockIdx.x] = sm[1023];
}

__global__ __launch_bounds__(1024) void k_scan2(int* __restrict__ bsums, int nb) {
    __shared__ int sm[1024];
    int v = (threadIdx.x < nb) ? bsums[threadIdx.x] : 0;
    sm[threadIdx.x] = v;
    __syncthreads();
    for (int o = 1; o < 1024; o <<= 1) {
        int t = (threadIdx.x >= o) ? sm[threadIdx.x - o] : 0;
        __syncthreads();
        sm[threadIdx.x] += t;
        __syncthreads();
    }
    if (threadIdx.x < nb) bsums[threadIdx.x] = sm[threadIdx.x] - v;  // exclusive
}

__global__ __launch_bounds__(256) void k_scan3(int* __restrict__ rowstart,
                                               const int* __restrict__ bsums, int n, int etot) {
    int i = blockIdx.x * blockDim.x + threadIdx.x;
    if (i < n) rowstart[i] += bsums[i >> 10];
    if (i == 0) rowstart[n] = etot;
}

__global__ __launch_bounds__(256) void k_scatter(const int* __restrict__ eraw, int e, int etot,
                                                 const int* __restrict__ flag,
                                                 const int* __restrict__ rowstart,
                                                 int* __restrict__ cursor, int* __restrict__ csr) {
    int i = blockIdx.x * blockDim.x + threadIdx.x;
    if (i >= etot) return;
    int s, d;
    if (i < e) {
        if (*flag == 0) { s = eraw[2 * i]; d = eraw[2 * (e + i)]; }
        else            { s = eraw[i];     d = eraw[e + i]; }
    } else {
        s = i - e; d = i - e;
    }
    int pos = rowstart[d] + atomicAdd(&cursor[d], 1);
    csr[pos] = s;
}

// va = W2 @ as2, vd = W2 @ ad2
__global__ __launch_bounds__(64) void k_prep(const float* __restrict__ W2,
                                             const float* __restrict__ as2,
                                             const float* __restrict__ ad2,
                                             float* __restrict__ va, float* __restrict__ vd) {
    int k = threadIdx.x;
    float sa = 0.f, sd = 0.f;
    for (int j = 0; j < 64; j++) {
        float w = W2[k * 64 + j];
        sa += w * as2[j];
        sd += w * ad2[j];
    }
    va[k] = sa;
    vd[k] = sd;
}

// layer 0: h = x[N,2] @ W[2,64]; per-head (4x16) alpha dots. One wave per node.
__global__ __launch_bounds__(256) void k_feat0(const float* __restrict__ Xin,
                                               const float* __restrict__ W,
                                               const float* __restrict__ Asrc,
                                               const float* __restrict__ Adst,
                                               float* __restrict__ H, float* __restrict__ asn,
                                               float* __restrict__ adn, int n) {
    const int wv = threadIdx.x >> 6, ln = threadIdx.x & 63;
    const float w0 = W[ln], w1 = W[64 + ln];
    const float a_s = Asrc[ln], a_d = Adst[ln];
    for (int node = blockIdx.x * 4 + wv; node < n; node += gridDim.x * 4) {
        float x0 = Xin[node * 2 + 0], x1 = Xin[node * 2 + 1];
        float acc = fmaf(x1, w1, x0 * w0);
        float ts = acc * a_s, td = acc * a_d;
        #pragma unroll
        for (int o = 1; o < 16; o <<= 1) {
            ts += __shfl_xor(ts, o, 16);
            td += __shfl_xor(td, o, 16);
        }
        H[node * 64 + ln] = acc;
        if ((ln & 15) == 0) {
            asn[node * 4 + (ln >> 4)] = ts;
            adn[node * 4 + (ln >> 4)] = td;
        }
    }
}

// layer 1: h = X[N,64] @ W[64,64] + per-head alpha dots.
// 16-lane group per node (4 nodes/wave, 16 nodes/block), lane q owns float4.
__global__ __launch_bounds__(256) void k_feat64(const float4* __restrict__ X4,
                                                const float* __restrict__ W,
                                                const float* __restrict__ Asrc,
                                                const float* __restrict__ Adst,
                                                float4* __restrict__ H4, float* __restrict__ asn,
                                                float* __restrict__ adn, int n) {
    __shared__ float Ws[64 * 64];
    for (int i = threadIdx.x; i < 64 * 64; i += 256) Ws[i] = W[i];
    __syncthreads();
    const float4* Ws4 = (const float4*)Ws;  // Ws4[k*16 + q]
    const int ln = threadIdx.x & 63;
    const int g = ln >> 4, q = ln & 15;
    const int grp = (threadIdx.x >> 6) * 4 + g;  // node slot 0..15 in block
    const float4 a_s4 = ((const float4*)Asrc)[q];
    const float4 a_d4 = ((const float4*)Adst)[q];
    for (int node = blockIdx.x * 16 + grp; node < n; node += gridDim.x * 16) {
        float4 xv = X4[node * 16 + q];
        float4 acc = make_float4(0.f, 0.f, 0.f, 0.f);
        #pragma unroll
        for (int k4 = 0; k4 < 16; k4++) {
            float bx = __shfl(xv.x, k4, 16);
            float by = __shfl(xv.y, k4, 16);
            float bz = __shfl(xv.z, k4, 16);
            float bw = __shfl(xv.w, k4, 16);
            float4 wr;
            wr = Ws4[(4 * k4 + 0) * 16 + q];
            acc.x = fmaf(bx, wr.x, acc.x); acc.y = fmaf(bx, wr.y, acc.y);
            acc.z = fmaf(bx, wr.z, acc.z); acc.w = fmaf(bx, wr.w, acc.w);
            wr = Ws4[(4 * k4 + 1) * 16 + q];
            acc.x = fmaf(by, wr.x, acc.x); acc.y = fmaf(by, wr.y, acc.y);
            acc.z = fmaf(by, wr.z, acc.z); acc.w = fmaf(by, wr.w, acc.w);
            wr = Ws4[(4 * k4 + 2) * 16 + q];
            acc.x = fmaf(bz, wr.x, acc.x); acc.y = fmaf(bz, wr.y, acc.y);
            acc.z = fmaf(bz, wr.z, acc.z); acc.w = fmaf(bz, wr.w, acc.w);
            wr = Ws4[(4 * k4 + 3) * 16 + q];
            acc.x = fmaf(bw, wr.x, acc.x); acc.y = fmaf(bw, wr.y, acc.y);
            acc.z = fmaf(bw, wr.z, acc.z); acc.w = fmaf(bw, wr.w, acc.w);
        }
        float ts = acc.x * a_s4.x + acc.y * a_s4.y + acc.z * a_s4.z + acc.w * a_s4.w;
        float td = acc.x * a_d4.x + acc.y * a_d4.y + acc.z * a_d4.z + acc.w * a_d4.w;
        ts += __shfl_xor(ts, 1); ts += __shfl_xor(ts, 2);  // sum over head's 4 quads
        td += __shfl_xor(td, 1); td += __shfl_xor(td, 2);
        H4[node * 16 + q] = acc;
        if ((q & 3) == 0) {
            asn[node * 4 + (q >> 2)] = ts;
            adn[node * 4 + (q >> 2)] = td;
        }
    }
}

// layer 2 alpha dots: asn[node] = X2row.va, adn[node] = X2row.vd
__global__ __launch_bounds__(256) void k_alpha2(const float4* __restrict__ X4,
                                                const float* __restrict__ va,
                                                const float* __restrict__ vd,
                                                float* __restrict__ asn, float* __restrict__ adn,
                                                int n) {
    const int ln = threadIdx.x & 63;
    const int g = ln >> 4, q = ln & 15;
    const int grp = (threadIdx.x >> 6) * 4 + g;
    const float4 va4 = ((const float4*)va)[q];
    const float4 vd4 = ((const float4*)vd)[q];
    for (int node = blockIdx.x * 16 + grp; node < n; node += gridDim.x * 16) {
        float4 xv = X4[node * 16 + q];
        float ts = xv.x * va4.x + xv.y * va4.y + xv.z * va4.z + xv.w * va4.w;
        float td = xv.x * vd4.x + xv.y * vd4.y + xv.z * vd4.z + xv.w * vd4.w;
        #pragma unroll
        for (int o = 1; o < 16; o <<= 1) {
            ts += __shfl_xor(ts, o);
            td += __shfl_xor(td, o);
        }
        if (q == 0) { asn[node] = ts; adn[node] = td; }
    }
}

// Fused segment softmax + aggregation, one wave per dst node.
// No max-shift (logits O(5), f32 exp safe); normalize by 1/sum at end.
// 16-lane group g handles edge (start+g, +4, ...); lane q owns channels 4q..4q+3.
// FINAL=false: Out = leaky(acc/sum + bias, 0.01); FINAL=true: Out = acc/sum.
template <int HEADS, bool FINAL>
__global__ __launch_bounds__(256) void k_edge(const float4* __restrict__ H4,
                                              const float* __restrict__ asn,
                                              const float* __restrict__ adn,
                                              const int* __restrict__ rowstart,
                                              const int* __restrict__ csr,
                                              const float* __restrict__ bias,
                                              float4* __restrict__ Out4, int n) {
    const int wv = threadIdx.x >> 6, ln = threadIdx.x & 63;
    const int node = blockIdx.x * 4 + wv;
    if (node >= n) return;
    const int g = ln >> 4, q = ln & 15;
    const int head = (HEADS == 4) ? (q >> 2) : 0;
    const int start = rowstart[node], end = rowstart[node + 1];
    const float adme = adn[node * HEADS + head];

    float4 acc = make_float4(0.f, 0.f, 0.f, 0.f);
    float sw = 0.f;
    for (int eg = start + g; eg < end; eg += 4) {
        int s = csr[eg];
        float l = LRELU(asn[s * HEADS + head] + adme, 0.2f);
        float w = __expf(l);
        sw += w;
        float4 hv = H4[s * 16 + q];
        acc.x = fmaf(w, hv.x, acc.x);
        acc.y = fmaf(w, hv.y, acc.y);
        acc.z = fmaf(w, hv.z, acc.z);
        acc.w = fmaf(w, hv.w, acc.w);
    }
    #pragma unroll
    for (int o = 16; o < 64; o <<= 1) {
        acc.x += __shfl_xor(acc.x, o);
        acc.y += __shfl_xor(acc.y, o);
        acc.z += __shfl_xor(acc.z, o);
        acc.w += __shfl_xor(acc.w, o);
        sw += __shfl_xor(sw, o);
    }
    if (ln < 16) {
        const float inv = 1.0f / sw;
        float4 res;
        res.x = acc.x * inv; res.y = acc.y * inv;
        res.z = acc.z * inv; res.w = acc.w * inv;
        if constexpr (!FINAL) {
            const float4 b4 = ((const float4*)bias)[q];
            res.x = LRELU(res.x + b4.x, 0.01f);
            res.y = LRELU(res.y + b4.y, 0.01f);
            res.z = LRELU(res.z + b4.z, 0.01f);
            res.w = LRELU(res.w + b4.w, 0.01f);
        }
        Out4[node * 16 + q] = res;
    }
}

// final dense: out = Agg[N,64] @ W2[64,64] + b2
__global__ __launch_bounds__(256) void k_out(const float4* __restrict__ A4,
                                             const float* __restrict__ W2,
                                             const float* __restrict__ b2,
                                             float4* __restrict__ Out4, int n) {
    __shared__ float Ws[64 * 64];
    for (int i = threadIdx.x; i < 64 * 64; i += 256) Ws[i] = W2[i];
    __syncthreads();
    const float4* Ws4 = (const float4*)Ws;
    const int ln = threadIdx.x & 63;
    const int g = ln >> 4, q = ln & 15;
    const int grp = (threadIdx.x >> 6) * 4 + g;
    const float4 b4 = ((const float4*)b2)[q];
    for (int node = blockIdx.x * 16 + grp; node < n; node += gridDim.x * 16) {
        float4 xv = A4[node * 16 + q];
        float4 acc = make_float4(0.f, 0.f, 0.f, 0.f);
        #pragma unroll
        for (int k4 = 0; k4 < 16; k4++) {
            float bx = __shfl(xv.x, k4, 16);
            float by = __shfl(xv.y, k4, 16);
            float bz = __shfl(xv.z, k4, 16);
            float bw = __shfl(xv.w, k4, 16);
            float4 wr;
            wr = Ws4[(4 * k4 + 0) * 16 + q];
            acc.x = fmaf(bx, wr.x, acc.x); acc.y = fmaf(bx, wr.y, acc.y);
            acc.z = fmaf(bx, wr.z, acc.z); acc.w = fmaf(bx, wr.w, acc.w);
            wr = Ws4[(4 * k4 + 1) * 16 + q];
            acc.x = fmaf(by, wr.x, acc.x); acc.y = fmaf(by, wr.y, acc.y);
            acc.z = fmaf(by, wr.z, acc.z); acc.w = fmaf(by, wr.w, acc.w);
            wr = Ws4[(4 * k4 + 2) * 16 + q];
            acc.x = fmaf(bz, wr.x, acc.x); acc.y = fmaf(bz, wr.y, acc.y);
            acc.z = fmaf(bz, wr.z, acc.z); acc.w = fmaf(bz, wr.w, acc.w);
            wr = Ws4[(4 * k4 + 3) * 16 + q];
            acc.x = fmaf(bw, wr.x, acc.x); acc.y = fmaf(bw, wr.y, acc.y);
            acc.z = fmaf(bw, wr.z, acc.z); acc.w = fmaf(bw, wr.w, acc.w);
        }
        acc.x += b4.x; acc.y += b4.y; acc.z += b4.z; acc.w += b4.w;
        Out4[node * 16 + q] = acc;
    }
}

extern "C" void kernel_launch(void* const* d_in, const int* in_sizes, int n_in, void* d_out,
                              int out_size, void* d_ws, size_t ws_size, hipStream_t stream) {
    const float* x = (const float*)d_in[0];
    const int* eraw = (const int*)d_in[1];
    const float* W0 = (const float*)d_in[2];
    const float* as0 = (const float*)d_in[3];
    const float* ad0 = (const float*)d_in[4];
    const float* b0 = (const float*)d_in[5];
    const float* W1 = (const float*)d_in[6];
    const float* as1 = (const float*)d_in[7];
    const float* ad1 = (const float*)d_in[8];
    const float* b1 = (const float*)d_in[9];
    const float* W2 = (const float*)d_in[10];
    const float* as2 = (const float*)d_in[11];
    const float* ad2 = (const float*)d_in[12];
    const float* b2 = (const float*)d_in[13];

    const int n = in_sizes[0] / 2;   // x [N,2]
    const int e = in_sizes[1] / 2;   // edge_index [2,E]
    const int etot = e + n;

    float* Xact = (float*)d_out;  // inter-layer activations in d_out (f32 [N,64])

    char* wp = (char*)d_ws;
    size_t off = 0;
    auto take = [&](size_t bytes) -> void* {
        void* p = wp + off;
        off = (off + bytes + 255) & ~(size_t)255;
        return p;
    };
    float* Hb     = (float*)take((size_t)n * 64 * 4);  // 25.6 MB (H / layer-2 Agg)
    float* asn    = (float*)take((size_t)n * 4 * 4);
    float* adn    = (float*)take((size_t)n * 4 * 4);
    int* deg      = (int*)take((size_t)2 * n * 4);     // deg + cursor
    int* cursor   = deg + n;
    int* rowstart = (int*)take((size_t)(n + 1) * 4);
    int* bsums    = (int*)take(1024 * 4);
    int* flag     = (int*)take(256);
    float* va     = (float*)take(64 * 4);
    float* vd     = (float*)take(64 * 4);
    int* csr      = (int*)take((size_t)etot * 4);
    (void)ws_size;

    hipMemsetAsync(deg, 0, (size_t)2 * n * 4, stream);
    hipMemsetAsync(flag, 0, 4, stream);

    const int tb = 256;
    k_detect<<<1, 1024, 0, stream>>>(eraw, e, flag);
    k_hist<<<(etot + tb - 1) / tb, tb, 0, stream>>>(eraw, e, etot, flag, deg);
    const int nb = (n + 1023) / 1024;
    k_scan1<<<nb, 1024, 0, stream>>>(deg, rowstart, bsums, n);
    k_scan2<<<1, 1024, 0, stream>>>(bsums, nb);
    k_scan3<<<(n + tb - 1) / tb, tb, 0, stream>>>(rowstart, bsums, n, etot);
    k_scatter<<<(etot + tb - 1) / tb, tb, 0, stream>>>(eraw, e, etot, flag, rowstart, cursor, csr);
    k_prep<<<1, 64, 0, stream>>>(W2, as2, ad2, va, vd);

    const int nodeBlocks4 = (n + 3) / 4;     // 4 nodes/block kernels
    const int nodeBlocks16 = (n + 15) / 16;  // 16 nodes/block kernels

    // layer 0
    k_feat0<<<nodeBlocks4, 256, 0, stream>>>(x, W0, as0, ad0, Hb, asn, adn, n);
    k_edge<4, false><<<nodeBlocks4, 256, 0, stream>>>((const float4*)Hb, asn, adn, rowstart, csr,
                                                      b0, (float4*)Xact, n);
    // layer 1
    k_feat64<<<nodeBlocks16, 256, 0, stream>>>((const float4*)Xact, W1, as1, ad1, (float4*)Hb,
                                               asn, adn, n);
    k_edge<4, false><<<nodeBlocks4, 256, 0, stream>>>((const float4*)Hb, asn, adn, rowstart, csr,
                                                      b1, (float4*)Xact, n);
    // layer 2 (linearity): alpha2 from X2; aggregate X2 -> Hb; dense + b2
    k_alpha2<<<nodeBlocks16, 256, 0, stream>>>((const float4*)Xact, va, vd, asn, adn, n);
    k_edge<1, true><<<nodeBlocks4, 256, 0, stream>>>((const float4*)Xact, asn, adn, rowstart, csr,
                                                     nullptr, (float4*)Hb, n);
    k_out<<<nodeBlocks16, 256, 0, stream>>>((const float4*)Hb, W2, b2, (float4*)d_out, n);
}

// Round 7
// 572.616 us; speedup vs baseline: 1.6714x; 1.1162x over previous
//
#include <hip/hip_runtime.h>
#include <hip/hip_bf16.h>

// ---------------------------------------------------------------------------
// GAT encoder: 3 GATConv layers, N=100K nodes, E=1.6M edges (+N self loops).
// f32 inputs/outputs, int32 edges (int64 fallback via on-device flag).
// R7: (1) radix-partitioned CSR scatter (dense pair streams -> XCD-local
//     scatter) to kill the 109MB write amplification seen in R6;
//     (2) bf16 storage for gathered feature rows (H0, H1, X2): halves k_edge
//     gather bytes. alpha scalars stay f32; all accumulation f32.
// ---------------------------------------------------------------------------

#define LRELU(x, a) fmaxf((x), (a) * (x))
typedef unsigned int u32;
typedef unsigned short u16;

__device__ __forceinline__ float bf2f(u16 v) { return __uint_as_float(((u32)v) << 16); }
__device__ __forceinline__ u16 f2bf(float f) {
    u32 u = __float_as_uint(f);
    return (u16)((u + 0x7FFF + ((u >> 16) & 1)) >> 16);  // RNE, finite data
}

// flag: 0 => int64 (all sampled high words zero), 1 => int32
__global__ __launch_bounds__(1024) void k_detect(const int* __restrict__ eraw, int e,
                                                 int* __restrict__ flag) {
    int i = threadIdx.x;
    long long step = (long long)e / 1024;
    if (step == 0) step = 1;
    long long pos = 2LL * (i * step) + 1;
    if (pos < 2LL * e && eraw[pos] != 0) atomicExch(flag, 1);
}

__global__ __launch_bounds__(256) void k_hist(const int* __restrict__ eraw, int e, int etot,
                                              const int* __restrict__ flag,
                                              int* __restrict__ deg) {
    int i = blockIdx.x * blockDim.x + threadIdx.x;
    if (i >= etot) return;
    int d;
    if (i < e) d = (*flag == 0) ? eraw[2 * (e + i)] : eraw[e + i];
    else d = i - e;
    atomicAdd(&deg[d], 1);
}

__global__ __launch_bounds__(1024) void k_scan1(const int* __restrict__ deg,
                                                int* __restrict__ rowstart,
                                                int* __restrict__ bsums, int n) {
    __shared__ int sm[1024];
    int i = blockIdx.x * 1024 + threadIdx.x;
    int v = (i < n) ? deg[i] : 0;
    sm[threadIdx.x] = v;
    __syncthreads();
    for (int o = 1; o < 1024; o <<= 1) {
        int t = (threadIdx.x >= o) ? sm[threadIdx.x - o] : 0;
        __syncthreads();
        sm[threadIdx.x] += t;
        __syncthreads();
    }
    if (i < n) rowstart[i] = sm[threadIdx.x] - v;  // exclusive
    if (threadIdx.x == 1023) bsums[blockIdx.x] = sm[1023];
}

__global__ __launch_bounds__(1024) void k_scan2(int* __restrict__ bsums, int nb) {
    __shared__ int sm[1024];
    int v = (threadIdx.x < nb) ? bsums[threadIdx.x] : 0;
    sm[threadIdx.x] = v;
    __syncthreads();
    for (int o = 1; o < 1024; o <<= 1) {
        int t = (threadIdx.x >= o) ? sm[threadIdx.x - o] : 0;
        __syncthreads();
        sm[threadIdx.x] += t;
        __syncthreads();
    }
    if (threadIdx.x < nb) bsums[threadIdx.x] = sm[threadIdx.x] - v;  // exclusive
}

__global__ __launch_bounds__(256) void k_scan3(int* __restrict__ rowstart,
                                               const int* __restrict__ bsums, int n, int etot) {
    int i = blockIdx.x * blockDim.x + threadIdx.x;
    if (i < n) rowstart[i] += bsums[i >> 10];
    if (i == 0) rowstart[n] = etot;
}

// va = W2 @ as2, vd = W2 @ ad2; also init per-bucket pair cursors from rowstart
__global__ __launch_bounds__(64) void k_prep(const float* __restrict__ W2,
                                             const float* __restrict__ as2,
                                             const float* __restrict__ ad2,
                                             const int* __restrict__ rowstart, int n,
                                             float* __restrict__ va, float* __restrict__ vd,
                                             int* __restrict__ gcnt) {
    int k = threadIdx.x;
    float sa = 0.f, sd = 0.f;
    for (int j = 0; j < 64; j++) {
        float w = W2[k * 64 + j];
        sa += w * as2[j];
        sd += w * ad2[j];
    }
    va[k] = sa;
    vd[k] = sd;
    if (k < 8) gcnt[k] = rowstart[(k * n + 7) / 8];
}

// Pass A: append (s,d) into dense per-bucket streams (bucket = dst range).
#define ACHUNK 2048
__global__ __launch_bounds__(256) void k_passA(const int* __restrict__ eraw, int e, int etot,
                                               const int* __restrict__ flag, int n,
                                               int2* __restrict__ pairs, int* __restrict__ gcnt) {
    __shared__ int cnt[8];
    if (threadIdx.x < 8) cnt[threadIdx.x] = 0;
    __syncthreads();
    const int base = blockIdx.x * ACHUNK;
    const bool i64 = (*flag == 0);
    int s_[8], d_[8], b_[8];
    #pragma unroll
    for (int j = 0; j < 8; j++) {
        int i = base + j * 256 + threadIdx.x;
        if (i < etot) {
            int s, d;
            if (i < e) {
                if (i64) { s = eraw[2 * i]; d = eraw[2 * (e + i)]; }
                else     { s = eraw[i];     d = eraw[e + i]; }
            } else { s = i - e; d = i - e; }
            s_[j] = s; d_[j] = d;
            int b = (int)(((long long)d * 8) / n);
            b_[j] = b;
            atomicAdd(&cnt[b], 1);
        } else b_[j] = -1;
    }
    __syncthreads();
    if (threadIdx.x < 8) cnt[threadIdx.x] = atomicAdd(&gcnt[threadIdx.x], cnt[threadIdx.x]);
    __syncthreads();
    #pragma unroll
    for (int j = 0; j < 8; j++) {
        if (b_[j] >= 0) {
            int slot = atomicAdd(&cnt[b_[j]], 1);  // cnt now holds absolute offsets
            pairs[slot] = make_int2(s_[j], d_[j]);
        }
    }
}

// Pass B: bucket b processed by blocks with blockIdx%8==b (XCD round-robin
// heuristic -> csr/cursor writes stay in one XCD's L2). Perf-only assumption.
__global__ __launch_bounds__(256) void k_passB(const int2* __restrict__ pairs,
                                               const int* __restrict__ rowstart, int n,
                                               int* __restrict__ cursor, int* __restrict__ csr) {
    const int b = blockIdx.x & 7;
    const int sub = blockIdx.x >> 3;
    const int NSUB = gridDim.x >> 3;
    const int rb = rowstart[(b * n + 7) / 8];
    const int re = rowstart[((b + 1) * n + 7) / 8];
    const int len = re - rb;
    const int per = (len + NSUB - 1) / NSUB;
    const int lo = rb + sub * per;
    const int hi = min(lo + per, re);
    for (int i = lo + (int)threadIdx.x; i < hi; i += 256) {
        int2 p = pairs[i];
        int pos = rowstart[p.y] + atomicAdd(&cursor[p.y], 1);
        csr[pos] = p.x;
    }
}

// layer 0: h = x[N,2] @ W[2,64]; per-head (4x16) alpha dots -> bf16 H.
__global__ __launch_bounds__(256) void k_feat0(const float* __restrict__ Xin,
                                               const float* __restrict__ W,
                                               const float* __restrict__ Asrc,
                                               const float* __restrict__ Adst,
                                               u16* __restrict__ Hb, float* __restrict__ asn,
                                               float* __restrict__ adn, int n) {
    const int wv = threadIdx.x >> 6, ln = threadIdx.x & 63;
    const float w0 = W[ln], w1 = W[64 + ln];
    const float a_s = Asrc[ln], a_d = Adst[ln];
    for (int node = blockIdx.x * 4 + wv; node < n; node += gridDim.x * 4) {
        float x0 = Xin[node * 2 + 0], x1 = Xin[node * 2 + 1];
        float acc = fmaf(x1, w1, x0 * w0);
        float ts = acc * a_s, td = acc * a_d;
        #pragma unroll
        for (int o = 1; o < 16; o <<= 1) {
            ts += __shfl_xor(ts, o, 16);
            td += __shfl_xor(td, o, 16);
        }
        Hb[node * 64 + ln] = f2bf(acc);
        if ((ln & 15) == 0) {
            asn[node * 4 + (ln >> 4)] = ts;
            adn[node * 4 + (ln >> 4)] = td;
        }
    }
}

// layer 1: h = X[N,64](f32) @ W[64,64] -> bf16 H + per-head alpha dots.
// 16-lane group per node, lane q owns channels 4q..4q+3.
__global__ __launch_bounds__(256) void k_feat64(const float4* __restrict__ X4,
                                                const float* __restrict__ W,
                                                const float* __restrict__ Asrc,
                                                const float* __restrict__ Adst,
                                                u16* __restrict__ Hb, float* __restrict__ asn,
                                                float* __restrict__ adn, int n) {
    __shared__ float Ws[64 * 64];
    for (int i = threadIdx.x; i < 64 * 64; i += 256) Ws[i] = W[i];
    __syncthreads();
    const float4* Ws4 = (const float4*)Ws;
    const int ln = threadIdx.x & 63;
    const int g = ln >> 4, q = ln & 15;
    const int grp = (threadIdx.x >> 6) * 4 + g;
    const float4 a_s4 = ((const float4*)Asrc)[q];
    const float4 a_d4 = ((const float4*)Adst)[q];
    for (int node = blockIdx.x * 16 + grp; node < n; node += gridDim.x * 16) {
        float4 xv = X4[node * 16 + q];
        float4 acc = make_float4(0.f, 0.f, 0.f, 0.f);
        #pragma unroll
        for (int k4 = 0; k4 < 16; k4++) {
            float bx = __shfl(xv.x, k4, 16);
            float by = __shfl(xv.y, k4, 16);
            float bz = __shfl(xv.z, k4, 16);
            float bw = __shfl(xv.w, k4, 16);
            float4 wr;
            wr = Ws4[(4 * k4 + 0) * 16 + q];
            acc.x = fmaf(bx, wr.x, acc.x); acc.y = fmaf(bx, wr.y, acc.y);
            acc.z = fmaf(bx, wr.z, acc.z); acc.w = fmaf(bx, wr.w, acc.w);
            wr = Ws4[(4 * k4 + 1) * 16 + q];
            acc.x = fmaf(by, wr.x, acc.x); acc.y = fmaf(by, wr.y, acc.y);
            acc.z = fmaf(by, wr.z, acc.z); acc.w = fmaf(by, wr.w, acc.w);
            wr = Ws4[(4 * k4 + 2) * 16 + q];
            acc.x = fmaf(bz, wr.x, acc.x); acc.y = fmaf(bz, wr.y, acc.y);
            acc.z = fmaf(bz, wr.z, acc.z); acc.w = fmaf(bz, wr.w, acc.w);
            wr = Ws4[(4 * k4 + 3) * 16 + q];
            acc.x = fmaf(bw, wr.x, acc.x); acc.y = fmaf(bw, wr.y, acc.y);
            acc.z = fmaf(bw, wr.z, acc.z); acc.w = fmaf(bw, wr.w, acc.w);
        }
        float ts = acc.x * a_s4.x + acc.y * a_s4.y + acc.z * a_s4.z + acc.w * a_s4.w;
        float td = acc.x * a_d4.x + acc.y * a_d4.y + acc.z * a_d4.z + acc.w * a_d4.w;
        ts += __shfl_xor(ts, 1); ts += __shfl_xor(ts, 2);
        td += __shfl_xor(td, 1); td += __shfl_xor(td, 2);
        ushort4 hv;
        hv.x = f2bf(acc.x); hv.y = f2bf(acc.y); hv.z = f2bf(acc.z); hv.w = f2bf(acc.w);
        ((ushort4*)Hb)[node * 16 + q] = hv;
        if ((q & 3) == 0) {
            asn[node * 4 + (q >> 2)] = ts;
            adn[node * 4 + (q >> 2)] = td;
        }
    }
}

// layer 2 alpha dots from bf16 X2
__global__ __launch_bounds__(256) void k_alpha2(const u16* __restrict__ Xb,
                                                const float* __restrict__ va,
                                                const float* __restrict__ vd,
                                                float* __restrict__ asn, float* __restrict__ adn,
                                                int n) {
    const int ln = threadIdx.x & 63;
    const int g = ln >> 4, q = ln & 15;
    const int grp = (threadIdx.x >> 6) * 4 + g;
    const float4 va4 = ((const float4*)va)[q];
    const float4 vd4 = ((const float4*)vd)[q];
    for (int node = blockIdx.x * 16 + grp; node < n; node += gridDim.x * 16) {
        ushort4 xv = ((const ushort4*)Xb)[node * 16 + q];
        float x0 = bf2f(xv.x), x1 = bf2f(xv.y), x2 = bf2f(xv.z), x3 = bf2f(xv.w);
        float ts = x0 * va4.x + x1 * va4.y + x2 * va4.z + x3 * va4.w;
        float td = x0 * vd4.x + x1 * vd4.y + x2 * vd4.z + x3 * vd4.w;
        #pragma unroll
        for (int o = 1; o < 16; o <<= 1) {
            ts += __shfl_xor(ts, o);
            td += __shfl_xor(td, o);
        }
        if (q == 0) { asn[node] = ts; adn[node] = td; }
    }
}

// Fused segment softmax + aggregation, one wave per dst node, bf16 H gather.
// OUTMODE 0: f32 out = leaky(acc/sum + bias, 0.01)   (layer-0 -> X1 in d_out)
// OUTMODE 1: bf16 out = leaky(acc/sum + bias, 0.01)  (layer-1 -> Xb2)
// OUTMODE 2: f32 out = acc/sum                       (layer-2 aggregation)
template <int HEADS, int OUTMODE>
__global__ __launch_bounds__(256) void k_edge(const u16* __restrict__ Hb,
                                              const float* __restrict__ asn,
                                              const float* __restrict__ adn,
                                              const int* __restrict__ rowstart,
                                              const int* __restrict__ csr,
                                              const float* __restrict__ bias,
                                              float4* __restrict__ Outf,
                                              u16* __restrict__ Outb, int n) {
    const int wv = threadIdx.x >> 6, ln = threadIdx.x & 63;
    const int node = blockIdx.x * 4 + wv;
    if (node >= n) return;
    const int g = ln >> 4, q = ln & 15;
    const int head = (HEADS == 4) ? (q >> 2) : 0;
    const int start = rowstart[node], end = rowstart[node + 1];
    const float adme = adn[node * HEADS + head];

    float4 acc = make_float4(0.f, 0.f, 0.f, 0.f);
    float sw = 0.f;
    for (int eg = start + g; eg < end; eg += 4) {
        int s = csr[eg];
        float l = LRELU(asn[s * HEADS + head] + adme, 0.2f);
        float w = __expf(l);
        sw += w;
        ushort4 hv = ((const ushort4*)Hb)[s * 16 + q];
        acc.x = fmaf(w, bf2f(hv.x), acc.x);
        acc.y = fmaf(w, bf2f(hv.y), acc.y);
        acc.z = fmaf(w, bf2f(hv.z), acc.z);
        acc.w = fmaf(w, bf2f(hv.w), acc.w);
    }
    #pragma unroll
    for (int o = 16; o < 64; o <<= 1) {
        acc.x += __shfl_xor(acc.x, o);
        acc.y += __shfl_xor(acc.y, o);
        acc.z += __shfl_xor(acc.z, o);
        acc.w += __shfl_xor(acc.w, o);
        sw += __shfl_xor(sw, o);
    }
    if (ln < 16) {
        const float inv = 1.0f / sw;
        float4 res;
        res.x = acc.x * inv; res.y = acc.y * inv;
        res.z = acc.z * inv; res.w = acc.w * inv;
        if constexpr (OUTMODE != 2) {
            const float4 b4 = ((const float4*)bias)[q];
            res.x = LRELU(res.x + b4.x, 0.01f);
            res.y = LRELU(res.y + b4.y, 0.01f);
            res.z = LRELU(res.z + b4.z, 0.01f);
            res.w = LRELU(res.w + b4.w, 0.01f);
        }
        if constexpr (OUTMODE == 1) {
            ushort4 rb;
            rb.x = f2bf(res.x); rb.y = f2bf(res.y); rb.z = f2bf(res.z); rb.w = f2bf(res.w);
            ((ushort4*)Outb)[node * 16 + q] = rb;
        } else {
            Outf[node * 16 + q] = res;
        }
    }
}

// final dense (in-place on d_out): out = Agg[N,64] @ W2 + b2
__global__ __launch_bounds__(256) void k_out(const float4* __restrict__ A4,
                                             const float* __restrict__ W2,
                                             const float* __restrict__ b2,
                                             float4* __restrict__ Out4, int n) {
    __shared__ float Ws[64 * 64];
    for (int i = threadIdx.x; i < 64 * 64; i += 256) Ws[i] = W2[i];
    __syncthreads();
    const float4* Ws4 = (const float4*)Ws;
    const int ln = threadIdx.x & 63;
    const int g = ln >> 4, q = ln & 15;
    const int grp = (threadIdx.x >> 6) * 4 + g;
    const float4 b4 = ((const float4*)b2)[q];
    for (int node = blockIdx.x * 16 + grp; node < n; node += gridDim.x * 16) {
        float4 xv = A4[node * 16 + q];
        float4 acc = make_float4(0.f, 0.f, 0.f, 0.f);
        #pragma unroll
        for (int k4 = 0; k4 < 16; k4++) {
            float bx = __shfl(xv.x, k4, 16);
            float by = __shfl(xv.y, k4, 16);
            float bz = __shfl(xv.z, k4, 16);
            float bw = __shfl(xv.w, k4, 16);
            float4 wr;
            wr = Ws4[(4 * k4 + 0) * 16 + q];
            acc.x = fmaf(bx, wr.x, acc.x); acc.y = fmaf(bx, wr.y, acc.y);
            acc.z = fmaf(bx, wr.z, acc.z); acc.w = fmaf(bx, wr.w, acc.w);
            wr = Ws4[(4 * k4 + 1) * 16 + q];
            acc.x = fmaf(by, wr.x, acc.x); acc.y = fmaf(by, wr.y, acc.y);
            acc.z = fmaf(by, wr.z, acc.z); acc.w = fmaf(by, wr.w, acc.w);
            wr = Ws4[(4 * k4 + 2) * 16 + q];
            acc.x = fmaf(bz, wr.x, acc.x); acc.y = fmaf(bz, wr.y, acc.y);
            acc.z = fmaf(bz, wr.z, acc.z); acc.w = fmaf(bz, wr.w, acc.w);
            wr = Ws4[(4 * k4 + 3) * 16 + q];
            acc.x = fmaf(bw, wr.x, acc.x); acc.y = fmaf(bw, wr.y, acc.y);
            acc.z = fmaf(bw, wr.z, acc.z); acc.w = fmaf(bw, wr.w, acc.w);
        }
        acc.x += b4.x; acc.y += b4.y; acc.z += b4.z; acc.w += b4.w;
        Out4[node * 16 + q] = acc;
    }
}

extern "C" void kernel_launch(void* const* d_in, const int* in_sizes, int n_in, void* d_out,
                              int out_size, void* d_ws, size_t ws_size, hipStream_t stream) {
    const float* x = (const float*)d_in[0];
    const int* eraw = (const int*)d_in[1];
    const float* W0 = (const float*)d_in[2];
    const float* as0 = (const float*)d_in[3];
    const float* ad0 = (const float*)d_in[4];
    const float* b0 = (const float*)d_in[5];
    const float* W1 = (const float*)d_in[6];
    const float* as1 = (const float*)d_in[7];
    const float* ad1 = (const float*)d_in[8];
    const float* b1 = (const float*)d_in[9];
    const float* W2 = (const float*)d_in[10];
    const float* as2 = (const float*)d_in[11];
    const float* ad2 = (const float*)d_in[12];
    const float* b2 = (const float*)d_in[13];

    const int n = in_sizes[0] / 2;   // x [N,2]
    const int e = in_sizes[1] / 2;   // edge_index [2,E]
    const int etot = e + n;

    char* wp = (char*)d_ws;
    size_t off = 0;
    auto take = [&](size_t bytes) -> void* {
        void* p = wp + off;
        off = (off + bytes + 255) & ~(size_t)255;
        return p;
    };
    // union region: Hbf (bf16 N*64) + Xb2 (bf16 N*64) overlap pairs (int2*etot)
    size_t hsz = (size_t)n * 64 * 2;
    size_t usz = 2 * hsz > (size_t)etot * 8 ? 2 * hsz : (size_t)etot * 8;
    char* ubase   = (char*)take(usz);
    u16* Hbf      = (u16*)ubase;
    u16* Xb2      = (u16*)(ubase + hsz);
    int2* pairs   = (int2*)ubase;              // dead before Hbf/Xb2 are written
    float* asn    = (float*)take((size_t)n * 4 * 4);
    float* adn    = (float*)take((size_t)n * 4 * 4);
    int* deg      = (int*)take((size_t)2 * n * 4);   // deg + cursor
    int* cursor   = deg + n;
    int* rowstart = (int*)take((size_t)(n + 1) * 4);
    int* bsums    = (int*)take(1024 * 4);
    int* flag     = (int*)take(256);
    float* va     = (float*)take(64 * 4);
    float* vd     = (float*)take(64 * 4);
    int* gcnt     = (int*)take(256);
    int* csr      = (int*)take((size_t)etot * 4);
    (void)ws_size;

    hipMemsetAsync(deg, 0, (size_t)2 * n * 4, stream);
    hipMemsetAsync(flag, 0, 4, stream);

    const int tb = 256;
    k_detect<<<1, 1024, 0, stream>>>(eraw, e, flag);
    k_hist<<<(etot + tb - 1) / tb, tb, 0, stream>>>(eraw, e, etot, flag, deg);
    const int nb = (n + 1023) / 1024;
    k_scan1<<<nb, 1024, 0, stream>>>(deg, rowstart, bsums, n);
    k_scan2<<<1, 1024, 0, stream>>>(bsums, nb);
    k_scan3<<<(n + tb - 1) / tb, tb, 0, stream>>>(rowstart, bsums, n, etot);
    k_prep<<<1, 64, 0, stream>>>(W2, as2, ad2, rowstart, n, va, vd, gcnt);
    k_passA<<<(etot + ACHUNK - 1) / ACHUNK, 256, 0, stream>>>(eraw, e, etot, flag, n, pairs, gcnt);
    k_passB<<<1536, 256, 0, stream>>>(pairs, rowstart, n, cursor, csr);

    const int nodeBlocks4 = (n + 3) / 4;
    const int nodeBlocks16 = (n + 15) / 16;
    float* Xact = (float*)d_out;  // f32 X1 activations, later Agg, finally output

    // layer 0
    k_feat0<<<nodeBlocks4, 256, 0, stream>>>(x, W0, as0, ad0, Hbf, asn, adn, n);
    k_edge<4, 0><<<nodeBlocks4, 256, 0, stream>>>(Hbf, asn, adn, rowstart, csr, b0,
                                                  (float4*)Xact, nullptr, n);
    // layer 1
    k_feat64<<<nodeBlocks16, 256, 0, stream>>>((const float4*)Xact, W1, as1, ad1, Hbf,
                                               asn, adn, n);
    k_edge<4, 1><<<nodeBlocks4, 256, 0, stream>>>(Hbf, asn, adn, rowstart, csr, b1,
                                                  nullptr, Xb2, n);
    // layer 2 (linearity): alpha2 from Xb2; aggregate Xb2 -> Agg(d_out); dense in-place
    k_alpha2<<<nodeBlocks16, 256, 0, stream>>>(Xb2, va, vd, asn, adn, n);
    k_edge<1, 2><<<nodeBlocks4, 256, 0, stream>>>(Xb2, asn, adn, rowstart, csr, nullptr,
                                                  (float4*)Xact, nullptr, n);
    k_out<<<nodeBlocks16, 256, 0, stream>>>((const float4*)Xact, W2, b2, (float4*)d_out, n);
}

// Round 8
// 553.888 us; speedup vs baseline: 1.7279x; 1.0338x over previous
//
#include <hip/hip_runtime.h>
#include <hip/hip_bf16.h>

// ---------------------------------------------------------------------------
// GAT encoder: 3 GATConv layers, N=100K nodes, E=1.6M edges (+N self loops).
// f32 inputs/outputs, int32 edges (int64 fallback via on-device flag).
// R8: dense 64x64 transforms (k_feat64, k_out) rewritten: W register-resident
//     per lane (64 VGPRs, static unroll), one wave per node, no LDS, no
//     per-block W staging (R7's k_out was 10% occupancy, LDS-fill bound).
//     k_alpha2 fused into k_edge<4,1> epilogue (writes asn2/adn2, separate
//     buffers to avoid racing layer-1 alpha reads).
// ---------------------------------------------------------------------------

#define LRELU(x, a) fmaxf((x), (a) * (x))
typedef unsigned int u32;
typedef unsigned short u16;

__device__ __forceinline__ float bf2f(u16 v) { return __uint_as_float(((u32)v) << 16); }
__device__ __forceinline__ u16 f2bf(float f) {
    u32 u = __float_as_uint(f);
    return (u16)((u + 0x7FFF + ((u >> 16) & 1)) >> 16);  // RNE, finite data
}

// flag: 0 => int64 (all sampled high words zero), 1 => int32
__global__ __launch_bounds__(1024) void k_detect(const int* __restrict__ eraw, int e,
                                                 int* __restrict__ flag) {
    int i = threadIdx.x;
    long long step = (long long)e / 1024;
    if (step == 0) step = 1;
    long long pos = 2LL * (i * step) + 1;
    if (pos < 2LL * e && eraw[pos] != 0) atomicExch(flag, 1);
}

__global__ __launch_bounds__(256) void k_hist(const int* __restrict__ eraw, int e, int etot,
                                              const int* __restrict__ flag,
                                              int* __restrict__ deg) {
    int i = blockIdx.x * blockDim.x + threadIdx.x;
    if (i >= etot) return;
    int d;
    if (i < e) d = (*flag == 0) ? eraw[2 * (e + i)] : eraw[e + i];
    else d = i - e;
    atomicAdd(&deg[d], 1);
}

__global__ __launch_bounds__(1024) void k_scan1(const int* __restrict__ deg,
                                                int* __restrict__ rowstart,
                                                int* __restrict__ bsums, int n) {
    __shared__ int sm[1024];
    int i = blockIdx.x * 1024 + threadIdx.x;
    int v = (i < n) ? deg[i] : 0;
    sm[threadIdx.x] = v;
    __syncthreads();
    for (int o = 1; o < 1024; o <<= 1) {
        int t = (threadIdx.x >= o) ? sm[threadIdx.x - o] : 0;
        __syncthreads();
        sm[threadIdx.x] += t;
        __syncthreads();
    }
    if (i < n) rowstart[i] = sm[threadIdx.x] - v;  // exclusive
    if (threadIdx.x == 1023) bsums[blockIdx.x] = sm[1023];
}

__global__ __launch_bounds__(1024) void k_scan2(int* __restrict__ bsums, int nb) {
    __shared__ int sm[1024];
    int v = (threadIdx.x < nb) ? bsums[threadIdx.x] : 0;
    sm[threadIdx.x] = v;
    __syncthreads();
    for (int o = 1; o < 1024; o <<= 1) {
        int t = (threadIdx.x >= o) ? sm[threadIdx.x - o] : 0;
        __syncthreads();
        sm[threadIdx.x] += t;
        __syncthreads();
    }
    if (threadIdx.x < nb) bsums[threadIdx.x] = sm[threadIdx.x] - v;  // exclusive
}

__global__ __launch_bounds__(256) void k_scan3(int* __restrict__ rowstart,
                                               const int* __restrict__ bsums, int n, int etot) {
    int i = blockIdx.x * blockDim.x + threadIdx.x;
    if (i < n) rowstart[i] += bsums[i >> 10];
    if (i == 0) rowstart[n] = etot;
}

// va = W2 @ as2, vd = W2 @ ad2; also init per-bucket pair cursors from rowstart
__global__ __launch_bounds__(64) void k_prep(const float* __restrict__ W2,
                                             const float* __restrict__ as2,
                                             const float* __restrict__ ad2,
                                             const int* __restrict__ rowstart, int n,
                                             float* __restrict__ va, float* __restrict__ vd,
                                             int* __restrict__ gcnt) {
    int k = threadIdx.x;
    float sa = 0.f, sd = 0.f;
    for (int j = 0; j < 64; j++) {
        float w = W2[k * 64 + j];
        sa += w * as2[j];
        sd += w * ad2[j];
    }
    va[k] = sa;
    vd[k] = sd;
    if (k < 8) gcnt[k] = rowstart[(k * n + 7) / 8];
}

// Pass A: append (s,d) into dense per-bucket streams (bucket = dst range).
#define ACHUNK 2048
__global__ __launch_bounds__(256) void k_passA(const int* __restrict__ eraw, int e, int etot,
                                               const int* __restrict__ flag, int n,
                                               int2* __restrict__ pairs, int* __restrict__ gcnt) {
    __shared__ int cnt[8];
    if (threadIdx.x < 8) cnt[threadIdx.x] = 0;
    __syncthreads();
    const int base = blockIdx.x * ACHUNK;
    const bool i64 = (*flag == 0);
    int s_[8], d_[8], b_[8];
    #pragma unroll
    for (int j = 0; j < 8; j++) {
        int i = base + j * 256 + threadIdx.x;
        if (i < etot) {
            int s, d;
            if (i < e) {
                if (i64) { s = eraw[2 * i]; d = eraw[2 * (e + i)]; }
                else     { s = eraw[i];     d = eraw[e + i]; }
            } else { s = i - e; d = i - e; }
            s_[j] = s; d_[j] = d;
            int b = (int)(((long long)d * 8) / n);
            b_[j] = b;
            atomicAdd(&cnt[b], 1);
        } else b_[j] = -1;
    }
    __syncthreads();
    if (threadIdx.x < 8) cnt[threadIdx.x] = atomicAdd(&gcnt[threadIdx.x], cnt[threadIdx.x]);
    __syncthreads();
    #pragma unroll
    for (int j = 0; j < 8; j++) {
        if (b_[j] >= 0) {
            int slot = atomicAdd(&cnt[b_[j]], 1);  // cnt now holds absolute offsets
            pairs[slot] = make_int2(s_[j], d_[j]);
        }
    }
}

// Pass B: bucket b processed by blocks with blockIdx%8==b (XCD round-robin
// heuristic -> csr/cursor writes stay in one XCD's L2). Perf-only assumption.
__global__ __launch_bounds__(256) void k_passB(const int2* __restrict__ pairs,
                                               const int* __restrict__ rowstart, int n,
                                               int* __restrict__ cursor, int* __restrict__ csr) {
    const int b = blockIdx.x & 7;
    const int sub = blockIdx.x >> 3;
    const int NSUB = gridDim.x >> 3;
    const int rb = rowstart[(b * n + 7) / 8];
    const int re = rowstart[((b + 1) * n + 7) / 8];
    const int len = re - rb;
    const int per = (len + NSUB - 1) / NSUB;
    const int lo = rb + sub * per;
    const int hi = min(lo + per, re);
    for (int i = lo + (int)threadIdx.x; i < hi; i += 256) {
        int2 p = pairs[i];
        int pos = rowstart[p.y] + atomicAdd(&cursor[p.y], 1);
        csr[pos] = p.x;
    }
}

// layer 0: h = x[N,2] @ W[2,64]; per-head (4x16) alpha dots -> bf16 H.
__global__ __launch_bounds__(256) void k_feat0(const float* __restrict__ Xin,
                                               const float* __restrict__ W,
                                               const float* __restrict__ Asrc,
                                               const float* __restrict__ Adst,
                                               u16* __restrict__ Hb, float* __restrict__ asn,
                                               float* __restrict__ adn, int n) {
    const int wv = threadIdx.x >> 6, ln = threadIdx.x & 63;
    const float w0 = W[ln], w1 = W[64 + ln];
    const float a_s = Asrc[ln], a_d = Adst[ln];
    for (int node = blockIdx.x * 4 + wv; node < n; node += gridDim.x * 4) {
        float x0 = Xin[node * 2 + 0], x1 = Xin[node * 2 + 1];
        float acc = fmaf(x1, w1, x0 * w0);
        float ts = acc * a_s, td = acc * a_d;
        #pragma unroll
        for (int o = 1; o < 16; o <<= 1) {
            ts += __shfl_xor(ts, o, 16);
            td += __shfl_xor(td, o, 16);
        }
        Hb[node * 64 + ln] = f2bf(acc);
        if ((ln & 15) == 0) {
            asn[node * 4 + (ln >> 4)] = ts;
            adn[node * 4 + (ln >> 4)] = td;
        }
    }
}

// layer 1: h = X[N,64](f32) @ W[64,64] -> bf16 H + per-head alpha dots.
// One wave per node; lane = output channel; W column register-resident.
__global__ __launch_bounds__(256) void k_feat64(const float* __restrict__ Xin,
                                                const float* __restrict__ W,
                                                const float* __restrict__ Asrc,
                                                const float* __restrict__ Adst,
                                                u16* __restrict__ Hb, float* __restrict__ asn,
                                                float* __restrict__ adn, int n) {
    const int wv = threadIdx.x >> 6, ln = threadIdx.x & 63;
    float wreg[64];
    #pragma unroll
    for (int k = 0; k < 64; k++) wreg[k] = W[k * 64 + ln];
    const float a_s = Asrc[ln], a_d = Adst[ln];
    for (int node = blockIdx.x * 4 + wv; node < n; node += gridDim.x * 4) {
        float xv = Xin[node * 64 + ln];
        float acc = 0.f;
        #pragma unroll
        for (int k = 0; k < 64; k++) acc = fmaf(__shfl(xv, k), wreg[k], acc);
        float ts = acc * a_s, td = acc * a_d;
        #pragma unroll
        for (int o = 1; o < 16; o <<= 1) {
            ts += __shfl_xor(ts, o, 16);
            td += __shfl_xor(td, o, 16);
        }
        Hb[node * 64 + ln] = f2bf(acc);
        if ((ln & 15) == 0) {
            asn[node * 4 + (ln >> 4)] = ts;
            adn[node * 4 + (ln >> 4)] = td;
        }
    }
}

// Fused segment softmax + aggregation, one wave per dst node, bf16 H gather.
// OUTMODE 0: f32 out = leaky(acc/sum + bias, 0.01)   (layer-0 -> X1 in d_out)
// OUTMODE 1: bf16 out = leaky(acc/sum + bias, 0.01)  (layer-1 -> Xb2)
//            + fused layer-2 alpha dots (va/vd) -> asn2/adn2
// OUTMODE 2: f32 out = acc/sum                       (layer-2 aggregation)
template <int HEADS, int OUTMODE>
__global__ __launch_bounds__(256) void k_edge(const u16* __restrict__ Hb,
                                              const float* __restrict__ asn,
                                              const float* __restrict__ adn,
                                              const int* __restrict__ rowstart,
                                              const int* __restrict__ csr,
                                              const float* __restrict__ bias,
                                              float4* __restrict__ Outf,
                                              u16* __restrict__ Outb,
                                              const float* __restrict__ va,
                                              const float* __restrict__ vd,
                                              float* __restrict__ asn2,
                                              float* __restrict__ adn2, int n) {
    const int wv = threadIdx.x >> 6, ln = threadIdx.x & 63;
    const int node = blockIdx.x * 4 + wv;
    if (node >= n) return;
    const int g = ln >> 4, q = ln & 15;
    const int head = (HEADS == 4) ? (q >> 2) : 0;
    const int start = rowstart[node], end = rowstart[node + 1];
    const float adme = adn[node * HEADS + head];

    float4 acc = make_float4(0.f, 0.f, 0.f, 0.f);
    float sw = 0.f;
    for (int eg = start + g; eg < end; eg += 4) {
        int s = csr[eg];
        float l = LRELU(asn[s * HEADS + head] + adme, 0.2f);
        float w = __expf(l);
        sw += w;
        ushort4 hv = ((const ushort4*)Hb)[s * 16 + q];
        acc.x = fmaf(w, bf2f(hv.x), acc.x);
        acc.y = fmaf(w, bf2f(hv.y), acc.y);
        acc.z = fmaf(w, bf2f(hv.z), acc.z);
        acc.w = fmaf(w, bf2f(hv.w), acc.w);
    }
    #pragma unroll
    for (int o = 16; o < 64; o <<= 1) {
        acc.x += __shfl_xor(acc.x, o);
        acc.y += __shfl_xor(acc.y, o);
        acc.z += __shfl_xor(acc.z, o);
        acc.w += __shfl_xor(acc.w, o);
        sw += __shfl_xor(sw, o);
    }
    if (ln < 16) {
        const float inv = 1.0f / sw;
        float4 res;
        res.x = acc.x * inv; res.y = acc.y * inv;
        res.z = acc.z * inv; res.w = acc.w * inv;
        if constexpr (OUTMODE != 2) {
            const float4 b4 = ((const float4*)bias)[q];
            res.x = LRELU(res.x + b4.x, 0.01f);
            res.y = LRELU(res.y + b4.y, 0.01f);
            res.z = LRELU(res.z + b4.z, 0.01f);
            res.w = LRELU(res.w + b4.w, 0.01f);
        }
        if constexpr (OUTMODE == 1) {
            ushort4 rb;
            rb.x = f2bf(res.x); rb.y = f2bf(res.y); rb.z = f2bf(res.z); rb.w = f2bf(res.w);
            ((ushort4*)Outb)[node * 16 + q] = rb;
            // fused layer-2 alpha dots: asn2[node] = X2row.va, adn2[node] = X2row.vd
            const float4 va4 = ((const float4*)va)[q];
            const float4 vd4 = ((const float4*)vd)[q];
            float ts = res.x * va4.x + res.y * va4.y + res.z * va4.z + res.w * va4.w;
            float td = res.x * vd4.x + res.y * vd4.y + res.z * vd4.z + res.w * vd4.w;
            #pragma unroll
            for (int o = 1; o < 16; o <<= 1) {
                ts += __shfl_xor(ts, o, 16);
                td += __shfl_xor(td, o, 16);
            }
            if (ln == 0) { asn2[node] = ts; adn2[node] = td; }
        } else {
            Outf[node * 16 + q] = res;
        }
    }
}

// final dense: out = Agg[N,64] @ W2 + b2. One wave per node, W register-resident.
// In-place on d_out (each wave reads its row fully before writing it).
__global__ __launch_bounds__(256) void k_out(const float* __restrict__ Agg,
                                             const float* __restrict__ W2,
                                             const float* __restrict__ b2,
                                             float* __restrict__ Out, int n) {
    const int wv = threadIdx.x >> 6, ln = threadIdx.x & 63;
    float wreg[64];
    #pragma unroll
    for (int k = 0; k < 64; k++) wreg[k] = W2[k * 64 + ln];
    const float bb = b2[ln];
    for (int node = blockIdx.x * 4 + wv; node < n; node += gridDim.x * 4) {
        float xv = Agg[node * 64 + ln];
        float acc = 0.f;
        #pragma unroll
        for (int k = 0; k < 64; k++) acc = fmaf(__shfl(xv, k), wreg[k], acc);
        Out[node * 64 + ln] = acc + bb;
    }
}

extern "C" void kernel_launch(void* const* d_in, const int* in_sizes, int n_in, void* d_out,
                              int out_size, void* d_ws, size_t ws_size, hipStream_t stream) {
    const float* x = (const float*)d_in[0];
    const int* eraw = (const int*)d_in[1];
    const float* W0 = (const float*)d_in[2];
    const float* as0 = (const float*)d_in[3];
    const float* ad0 = (const float*)d_in[4];
    const float* b0 = (const float*)d_in[5];
    const float* W1 = (const float*)d_in[6];
    const float* as1 = (const float*)d_in[7];
    const float* ad1 = (const float*)d_in[8];
    const float* b1 = (const float*)d_in[9];
    const float* W2 = (const float*)d_in[10];
    const float* as2 = (const float*)d_in[11];
    const float* ad2 = (const float*)d_in[12];
    const float* b2 = (const float*)d_in[13];

    const int n = in_sizes[0] / 2;   // x [N,2]
    const int e = in_sizes[1] / 2;   // edge_index [2,E]
    const int etot = e + n;

    char* wp = (char*)d_ws;
    size_t off = 0;
    auto take = [&](size_t bytes) -> void* {
        void* p = wp + off;
        off = (off + bytes + 255) & ~(size_t)255;
        return p;
    };
    // union region: Hbf (bf16 N*64) + Xb2 (bf16 N*64) overlap pairs (int2*etot)
    size_t hsz = (size_t)n * 64 * 2;
    size_t usz = 2 * hsz > (size_t)etot * 8 ? 2 * hsz : (size_t)etot * 8;
    char* ubase   = (char*)take(usz);
    u16* Hbf      = (u16*)ubase;
    u16* Xb2      = (u16*)(ubase + hsz);
    int2* pairs   = (int2*)ubase;              // dead before Hbf/Xb2 are written
    float* asn    = (float*)take((size_t)n * 4 * 4);
    float* adn    = (float*)take((size_t)n * 4 * 4);
    float* asn2   = (float*)take((size_t)n * 4);
    float* adn2   = (float*)take((size_t)n * 4);
    int* deg      = (int*)take((size_t)2 * n * 4);   // deg + cursor
    int* cursor   = deg + n;
    int* rowstart = (int*)take((size_t)(n + 1) * 4);
    int* bsums    = (int*)take(1024 * 4);
    int* flag     = (int*)take(256);
    float* va     = (float*)take(64 * 4);
    float* vd     = (float*)take(64 * 4);
    int* gcnt     = (int*)take(256);
    int* csr      = (int*)take((size_t)etot * 4);
    (void)ws_size;

    hipMemsetAsync(deg, 0, (size_t)2 * n * 4, stream);
    hipMemsetAsync(flag, 0, 4, stream);

    const int tb = 256;
    k_detect<<<1, 1024, 0, stream>>>(eraw, e, flag);
    k_hist<<<(etot + tb - 1) / tb, tb, 0, stream>>>(eraw, e, etot, flag, deg);
    const int nb = (n + 1023) / 1024;
    k_scan1<<<nb, 1024, 0, stream>>>(deg, rowstart, bsums, n);
    k_scan2<<<1, 1024, 0, stream>>>(bsums, nb);
    k_scan3<<<(n + tb - 1) / tb, tb, 0, stream>>>(rowstart, bsums, n, etot);
    k_prep<<<1, 64, 0, stream>>>(W2, as2, ad2, rowstart, n, va, vd, gcnt);
    k_passA<<<(etot + ACHUNK - 1) / ACHUNK, 256, 0, stream>>>(eraw, e, etot, flag, n, pairs, gcnt);
    k_passB<<<1536, 256, 0, stream>>>(pairs, rowstart, n, cursor, csr);

    const int nodeBlocks4 = (n + 3) / 4;
    const int gemmBlocks = 1024;  // grid-stride, W regs amortized ~25 nodes/wave
    float* Xact = (float*)d_out;  // f32 X1 activations, later Agg, finally output

    // layer 0
    k_feat0<<<nodeBlocks4, 256, 0, stream>>>(x, W0, as0, ad0, Hbf, asn, adn, n);
    k_edge<4, 0><<<nodeBlocks4, 256, 0, stream>>>(Hbf, asn, adn, rowstart, csr, b0,
                                                  (float4*)Xact, nullptr, nullptr, nullptr,
                                                  nullptr, nullptr, n);
    // layer 1 (k_edge also emits layer-2 alpha dots into asn2/adn2)
    k_feat64<<<gemmBlocks, 256, 0, stream>>>(Xact, W1, as1, ad1, Hbf, asn, adn, n);
    k_edge<4, 1><<<nodeBlocks4, 256, 0, stream>>>(Hbf, asn, adn, rowstart, csr, b1,
                                                  nullptr, Xb2, va, vd, asn2, adn2, n);
    // layer 2 (linearity): aggregate Xb2 -> Agg(d_out); dense in-place
    k_edge<1, 2><<<nodeBlocks4, 256, 0, stream>>>(Xb2, asn2, adn2, rowstart, csr, nullptr,
                                                  (float4*)Xact, nullptr, nullptr, nullptr,
                                                  nullptr, nullptr, n);
    k_out<<<gemmBlocks, 256, 0, stream>>>(Xact, W2, b2, (float*)d_out, n);
}

// Round 9
// 503.645 us; speedup vs baseline: 1.9003x; 1.0998x over previous
//
#include <hip/hip_runtime.h>
#include <hip/hip_bf16.h>

// ---------------------------------------------------------------------------
// GAT encoder: 3 GATConv layers, N=100K nodes, E=1.6M edges (+N self loops).
// f32 inputs/outputs, int32 edges (int64 fallback via on-device flag).
// R9: (1) __launch_bounds__(256,4) on dense kernels -> 128-VGPR budget so the
//     64-entry W column really lives in registers (R8: VGPR=64 forced W
//     rematerialization from L2 every node -> 88us, VALUBusy 23%).
//     (2) k_edge widened to 8 edges in flight (8-lane groups, uint4 = 8 bf16
//     channels per lane): half the trips, 2x outstanding loads.
// ---------------------------------------------------------------------------

#define LRELU(x, a) fmaxf((x), (a) * (x))
typedef unsigned int u32;
typedef unsigned short u16;

__device__ __forceinline__ float bf2f(u16 v) { return __uint_as_float(((u32)v) << 16); }
__device__ __forceinline__ u16 f2bf(float f) {
    u32 u = __float_as_uint(f);
    return (u16)((u + 0x7FFF + ((u >> 16) & 1)) >> 16);  // RNE, finite data
}

// flag: 0 => int64 (all sampled high words zero), 1 => int32
__global__ __launch_bounds__(1024) void k_detect(const int* __restrict__ eraw, int e,
                                                 int* __restrict__ flag) {
    int i = threadIdx.x;
    long long step = (long long)e / 1024;
    if (step == 0) step = 1;
    long long pos = 2LL * (i * step) + 1;
    if (pos < 2LL * e && eraw[pos] != 0) atomicExch(flag, 1);
}

__global__ __launch_bounds__(256) void k_hist(const int* __restrict__ eraw, int e, int etot,
                                              const int* __restrict__ flag,
                                              int* __restrict__ deg) {
    int i = blockIdx.x * blockDim.x + threadIdx.x;
    if (i >= etot) return;
    int d;
    if (i < e) d = (*flag == 0) ? eraw[2 * (e + i)] : eraw[e + i];
    else d = i - e;
    atomicAdd(&deg[d], 1);
}

__global__ __launch_bounds__(1024) void k_scan1(const int* __restrict__ deg,
                                                int* __restrict__ rowstart,
                                                int* __restrict__ bsums, int n) {
    __shared__ int sm[1024];
    int i = blockIdx.x * 1024 + threadIdx.x;
    int v = (i < n) ? deg[i] : 0;
    sm[threadIdx.x] = v;
    __syncthreads();
    for (int o = 1; o < 1024; o <<= 1) {
        int t = (threadIdx.x >= o) ? sm[threadIdx.x - o] : 0;
        __syncthreads();
        sm[threadIdx.x] += t;
        __syncthreads();
    }
    if (i < n) rowstart[i] = sm[threadIdx.x] - v;  // exclusive
    if (threadIdx.x == 1023) bsums[blockIdx.x] = sm[1023];
}

__global__ __launch_bounds__(1024) void k_scan2(int* __restrict__ bsums, int nb) {
    __shared__ int sm[1024];
    int v = (threadIdx.x < nb) ? bsums[threadIdx.x] : 0;
    sm[threadIdx.x] = v;
    __syncthreads();
    for (int o = 1; o < 1024; o <<= 1) {
        int t = (threadIdx.x >= o) ? sm[threadIdx.x - o] : 0;
        __syncthreads();
        sm[threadIdx.x] += t;
        __syncthreads();
    }
    if (threadIdx.x < nb) bsums[threadIdx.x] = sm[threadIdx.x] - v;  // exclusive
}

__global__ __launch_bounds__(256) void k_scan3(int* __restrict__ rowstart,
                                               const int* __restrict__ bsums, int n, int etot) {
    int i = blockIdx.x * blockDim.x + threadIdx.x;
    if (i < n) rowstart[i] += bsums[i >> 10];
    if (i == 0) rowstart[n] = etot;
}

// va = W2 @ as2, vd = W2 @ ad2; also init per-bucket pair cursors from rowstart
__global__ __launch_bounds__(64) void k_prep(const float* __restrict__ W2,
                                             const float* __restrict__ as2,
                                             const float* __restrict__ ad2,
                                             const int* __restrict__ rowstart, int n,
                                             float* __restrict__ va, float* __restrict__ vd,
                                             int* __restrict__ gcnt) {
    int k = threadIdx.x;
    float sa = 0.f, sd = 0.f;
    for (int j = 0; j < 64; j++) {
        float w = W2[k * 64 + j];
        sa += w * as2[j];
        sd += w * ad2[j];
    }
    va[k] = sa;
    vd[k] = sd;
    if (k < 8) gcnt[k] = rowstart[(k * n + 7) / 8];
}

// Pass A: append (s,d) into dense per-bucket streams (bucket = dst range).
#define ACHUNK 2048
__global__ __launch_bounds__(256) void k_passA(const int* __restrict__ eraw, int e, int etot,
                                               const int* __restrict__ flag, int n,
                                               int2* __restrict__ pairs, int* __restrict__ gcnt) {
    __shared__ int cnt[8];
    if (threadIdx.x < 8) cnt[threadIdx.x] = 0;
    __syncthreads();
    const int base = blockIdx.x * ACHUNK;
    const bool i64 = (*flag == 0);
    int s_[8], d_[8], b_[8];
    #pragma unroll
    for (int j = 0; j < 8; j++) {
        int i = base + j * 256 + threadIdx.x;
        if (i < etot) {
            int s, d;
            if (i < e) {
                if (i64) { s = eraw[2 * i]; d = eraw[2 * (e + i)]; }
                else     { s = eraw[i];     d = eraw[e + i]; }
            } else { s = i - e; d = i - e; }
            s_[j] = s; d_[j] = d;
            int b = (int)(((long long)d * 8) / n);
            b_[j] = b;
            atomicAdd(&cnt[b], 1);
        } else b_[j] = -1;
    }
    __syncthreads();
    if (threadIdx.x < 8) cnt[threadIdx.x] = atomicAdd(&gcnt[threadIdx.x], cnt[threadIdx.x]);
    __syncthreads();
    #pragma unroll
    for (int j = 0; j < 8; j++) {
        if (b_[j] >= 0) {
            int slot = atomicAdd(&cnt[b_[j]], 1);  // cnt now holds absolute offsets
            pairs[slot] = make_int2(s_[j], d_[j]);
        }
    }
}

// Pass B: bucket b processed by blocks with blockIdx%8==b (XCD round-robin
// heuristic -> csr/cursor writes stay in one XCD's L2). Perf-only assumption.
__global__ __launch_bounds__(256) void k_passB(const int2* __restrict__ pairs,
                                               const int* __restrict__ rowstart, int n,
                                               int* __restrict__ cursor, int* __restrict__ csr) {
    const int b = blockIdx.x & 7;
    const int sub = blockIdx.x >> 3;
    const int NSUB = gridDim.x >> 3;
    const int rb = rowstart[(b * n + 7) / 8];
    const int re = rowstart[((b + 1) * n + 7) / 8];
    const int len = re - rb;
    const int per = (len + NSUB - 1) / NSUB;
    const int lo = rb + sub * per;
    const int hi = min(lo + per, re);
    for (int i = lo + (int)threadIdx.x; i < hi; i += 256) {
        int2 p = pairs[i];
        int pos = rowstart[p.y] + atomicAdd(&cursor[p.y], 1);
        csr[pos] = p.x;
    }
}

// layer 0: h = x[N,2] @ W[2,64]; per-head (4x16) alpha dots -> bf16 H.
__global__ __launch_bounds__(256) void k_feat0(const float* __restrict__ Xin,
                                               const float* __restrict__ W,
                                               const float* __restrict__ Asrc,
                                               const float* __restrict__ Adst,
                                               u16* __restrict__ Hb, float* __restrict__ asn,
                                               float* __restrict__ adn, int n) {
    const int wv = threadIdx.x >> 6, ln = threadIdx.x & 63;
    const float w0 = W[ln], w1 = W[64 + ln];
    const float a_s = Asrc[ln], a_d = Adst[ln];
    for (int node = blockIdx.x * 4 + wv; node < n; node += gridDim.x * 4) {
        float x0 = Xin[node * 2 + 0], x1 = Xin[node * 2 + 1];
        float acc = fmaf(x1, w1, x0 * w0);
        float ts = acc * a_s, td = acc * a_d;
        #pragma unroll
        for (int o = 1; o < 16; o <<= 1) {
            ts += __shfl_xor(ts, o, 16);
            td += __shfl_xor(td, o, 16);
        }
        Hb[node * 64 + ln] = f2bf(acc);
        if ((ln & 15) == 0) {
            asn[node * 4 + (ln >> 4)] = ts;
            adn[node * 4 + (ln >> 4)] = td;
        }
    }
}

// layer 1: h = X[N,64](f32) @ W[64,64] -> bf16 H + per-head alpha dots.
// One wave per node; lane = output channel; W column register-resident
// (launch_bounds(.,4) -> 128-VGPR budget so wreg[64] stays in registers).
__global__ __launch_bounds__(256, 4) void k_feat64(const float* __restrict__ Xin,
                                                   const float* __restrict__ W,
                                                   const float* __restrict__ Asrc,
                                                   const float* __restrict__ Adst,
                                                   u16* __restrict__ Hb, float* __restrict__ asn,
                                                   float* __restrict__ adn, int n) {
    const int wv = threadIdx.x >> 6, ln = threadIdx.x & 63;
    float wreg[64];
    #pragma unroll
    for (int k = 0; k < 64; k++) wreg[k] = W[k * 64 + ln];
    const float a_s = Asrc[ln], a_d = Adst[ln];
    for (int node = blockIdx.x * 4 + wv; node < n; node += gridDim.x * 4) {
        float xv = Xin[node * 64 + ln];
        float acc = 0.f;
        #pragma unroll
        for (int k = 0; k < 64; k++) acc = fmaf(__shfl(xv, k), wreg[k], acc);
        float ts = acc * a_s, td = acc * a_d;
        #pragma unroll
        for (int o = 1; o < 16; o <<= 1) {
            ts += __shfl_xor(ts, o, 16);
            td += __shfl_xor(td, o, 16);
        }
        Hb[node * 64 + ln] = f2bf(acc);
        if ((ln & 15) == 0) {
            asn[node * 4 + (ln >> 4)] = ts;
            adn[node * 4 + (ln >> 4)] = td;
        }
    }
}

// Fused segment softmax + aggregation, one wave per dst node, bf16 H gather.
// 8 edges in flight: 8-lane group g handles edges start+g, +8, ...; lane q
// owns channels 8q..8q+7 (one uint4 = 8 bf16).
// OUTMODE 0: f32 out = leaky(acc/sum + bias, 0.01)   (layer-0 -> X1 in d_out)
// OUTMODE 1: bf16 out = leaky(acc/sum + bias, 0.01)  (layer-1 -> Xb2)
//            + fused layer-2 alpha dots (va/vd) -> asn2/adn2
// OUTMODE 2: f32 out = acc/sum                       (layer-2 aggregation)
template <int HEADS, int OUTMODE>
__global__ __launch_bounds__(256) void k_edge(const u16* __restrict__ Hb,
                                              const float* __restrict__ asn,
                                              const float* __restrict__ adn,
                                              const int* __restrict__ rowstart,
                                              const int* __restrict__ csr,
                                              const float* __restrict__ bias,
                                              float4* __restrict__ Outf,
                                              u16* __restrict__ Outb,
                                              const float* __restrict__ va,
                                              const float* __restrict__ vd,
                                              float* __restrict__ asn2,
                                              float* __restrict__ adn2, int n) {
    const int wv = threadIdx.x >> 6, ln = threadIdx.x & 63;
    const int node = blockIdx.x * 4 + wv;
    if (node >= n) return;
    const int g = ln >> 3, q = ln & 7;
    const int head = (HEADS == 4) ? (q >> 1) : 0;
    const int start = rowstart[node], end = rowstart[node + 1];
    const float adme = adn[node * HEADS + head];

    float a0 = 0.f, a1 = 0.f, a2 = 0.f, a3 = 0.f, a4 = 0.f, a5 = 0.f, a6 = 0.f, a7 = 0.f;
    float sw = 0.f;
    for (int eg = start + g; eg < end; eg += 8) {
        int s = csr[eg];
        float l = LRELU(asn[s * HEADS + head] + adme, 0.2f);
        float w = __expf(l);
        sw += w;
        uint4 hv = ((const uint4*)Hb)[s * 8 + q];
        a0 = fmaf(w, bf2f((u16)(hv.x & 0xffff)), a0);
        a1 = fmaf(w, bf2f((u16)(hv.x >> 16)), a1);
        a2 = fmaf(w, bf2f((u16)(hv.y & 0xffff)), a2);
        a3 = fmaf(w, bf2f((u16)(hv.y >> 16)), a3);
        a4 = fmaf(w, bf2f((u16)(hv.z & 0xffff)), a4);
        a5 = fmaf(w, bf2f((u16)(hv.z >> 16)), a5);
        a6 = fmaf(w, bf2f((u16)(hv.w & 0xffff)), a6);
        a7 = fmaf(w, bf2f((u16)(hv.w >> 16)), a7);
    }
    #pragma unroll
    for (int o = 8; o < 64; o <<= 1) {
        a0 += __shfl_xor(a0, o); a1 += __shfl_xor(a1, o);
        a2 += __shfl_xor(a2, o); a3 += __shfl_xor(a3, o);
        a4 += __shfl_xor(a4, o); a5 += __shfl_xor(a5, o);
        a6 += __shfl_xor(a6, o); a7 += __shfl_xor(a7, o);
        sw += __shfl_xor(sw, o);
    }
    if (ln < 8) {
        const float inv = 1.0f / sw;
        float r0 = a0 * inv, r1 = a1 * inv, r2 = a2 * inv, r3 = a3 * inv;
        float r4 = a4 * inv, r5 = a5 * inv, r6 = a6 * inv, r7 = a7 * inv;
        if constexpr (OUTMODE != 2) {
            const float4 bA = ((const float4*)bias)[2 * q];
            const float4 bB = ((const float4*)bias)[2 * q + 1];
            r0 = LRELU(r0 + bA.x, 0.01f); r1 = LRELU(r1 + bA.y, 0.01f);
            r2 = LRELU(r2 + bA.z, 0.01f); r3 = LRELU(r3 + bA.w, 0.01f);
            r4 = LRELU(r4 + bB.x, 0.01f); r5 = LRELU(r5 + bB.y, 0.01f);
            r6 = LRELU(r6 + bB.z, 0.01f); r7 = LRELU(r7 + bB.w, 0.01f);
        }
        if constexpr (OUTMODE == 1) {
            uint4 pb;
            pb.x = (u32)f2bf(r0) | ((u32)f2bf(r1) << 16);
            pb.y = (u32)f2bf(r2) | ((u32)f2bf(r3) << 16);
            pb.z = (u32)f2bf(r4) | ((u32)f2bf(r5) << 16);
            pb.w = (u32)f2bf(r6) | ((u32)f2bf(r7) << 16);
            ((uint4*)Outb)[node * 8 + q] = pb;
            // fused layer-2 alpha dots: asn2[node] = X2row.va, adn2[node] = X2row.vd
            const float4 vA = ((const float4*)va)[2 * q];
            const float4 vB = ((const float4*)va)[2 * q + 1];
            const float4 dA = ((const float4*)vd)[2 * q];
            const float4 dB = ((const float4*)vd)[2 * q + 1];
            float ts = r0 * vA.x + r1 * vA.y + r2 * vA.z + r3 * vA.w +
                       r4 * vB.x + r5 * vB.y + r6 * vB.z + r7 * vB.w;
            float td = r0 * dA.x + r1 * dA.y + r2 * dA.z + r3 * dA.w +
                       r4 * dB.x + r5 * dB.y + r6 * dB.z + r7 * dB.w;
            ts += __shfl_xor(ts, 1, 8); td += __shfl_xor(td, 1, 8);
            ts += __shfl_xor(ts, 2, 8); td += __shfl_xor(td, 2, 8);
            ts += __shfl_xor(ts, 4, 8); td += __shfl_xor(td, 4, 8);
            if (ln == 0) { asn2[node] = ts; adn2[node] = td; }
        } else {
            float4 oA = make_float4(r0, r1, r2, r3);
            float4 oB = make_float4(r4, r5, r6, r7);
            Outf[node * 16 + 2 * q] = oA;
            Outf[node * 16 + 2 * q + 1] = oB;
        }
    }
}

// final dense: out = Agg[N,64] @ W2 + b2. One wave per node, W register-resident.
// In-place on d_out (each wave reads its row fully before writing it).
__global__ __launch_bounds__(256, 4) void k_out(const float* __restrict__ Agg,
                                                const float* __restrict__ W2,
                                                const float* __restrict__ b2,
                                                float* __restrict__ Out, int n) {
    const int wv = threadIdx.x >> 6, ln = threadIdx.x & 63;
    float wreg[64];
    #pragma unroll
    for (int k = 0; k < 64; k++) wreg[k] = W2[k * 64 + ln];
    const float bb = b2[ln];
    for (int node = blockIdx.x * 4 + wv; node < n; node += gridDim.x * 4) {
        float xv = Agg[node * 64 + ln];
        float acc = 0.f;
        #pragma unroll
        for (int k = 0; k < 64; k++) acc = fmaf(__shfl(xv, k), wreg[k], acc);
        Out[node * 64 + ln] = acc + bb;
    }
}

extern "C" void kernel_launch(void* const* d_in, const int* in_sizes, int n_in, void* d_out,
                              int out_size, void* d_ws, size_t ws_size, hipStream_t stream) {
    const float* x = (const float*)d_in[0];
    const int* eraw = (const int*)d_in[1];
    const float* W0 = (const float*)d_in[2];
    const float* as0 = (const float*)d_in[3];
    const float* ad0 = (const float*)d_in[4];
    const float* b0 = (const float*)d_in[5];
    const float* W1 = (const float*)d_in[6];
    const float* as1 = (const float*)d_in[7];
    const float* ad1 = (const float*)d_in[8];
    const float* b1 = (const float*)d_in[9];
    const float* W2 = (const float*)d_in[10];
    const float* as2 = (const float*)d_in[11];
    const float* ad2 = (const float*)d_in[12];
    const float* b2 = (const float*)d_in[13];

    const int n = in_sizes[0] / 2;   // x [N,2]
    const int e = in_sizes[1] / 2;   // edge_index [2,E]
    const int etot = e + n;

    char* wp = (char*)d_ws;
    size_t off = 0;
    auto take = [&](size_t bytes) -> void* {
        void* p = wp + off;
        off = (off + bytes + 255) & ~(size_t)255;
        return p;
    };
    // union region: Hbf (bf16 N*64) + Xb2 (bf16 N*64) overlap pairs (int2*etot)
    size_t hsz = (size_t)n * 64 * 2;
    size_t usz = 2 * hsz > (size_t)etot * 8 ? 2 * hsz : (size_t)etot * 8;
    char* ubase   = (char*)take(usz);
    u16* Hbf      = (u16*)ubase;
    u16* Xb2      = (u16*)(ubase + hsz);
    int2* pairs   = (int2*)ubase;              // dead before Hbf/Xb2 are written
    float* asn    = (float*)take((size_t)n * 4 * 4);
    float* adn    = (float*)take((size_t)n * 4 * 4);
    float* asn2   = (float*)take((size_t)n * 4);
    float* adn2   = (float*)take((size_t)n * 4);
    int* deg      = (int*)take((size_t)2 * n * 4);   // deg + cursor
    int* cursor   = deg + n;
    int* rowstart = (int*)take((size_t)(n + 1) * 4);
    int* bsums    = (int*)take(1024 * 4);
    int* flag     = (int*)take(256);
    float* va     = (float*)take(64 * 4);
    float* vd     = (float*)take(64 * 4);
    int* gcnt     = (int*)take(256);
    int* csr      = (int*)take((size_t)etot * 4);
    (void)ws_size;

    hipMemsetAsync(deg, 0, (size_t)2 * n * 4, stream);
    hipMemsetAsync(flag, 0, 4, stream);

    const int tb = 256;
    k_detect<<<1, 1024, 0, stream>>>(eraw, e, flag);
    k_hist<<<(etot + tb - 1) / tb, tb, 0, stream>>>(eraw, e, etot, flag, deg);
    const int nb = (n + 1023) / 1024;
    k_scan1<<<nb, 1024, 0, stream>>>(deg, rowstart, bsums, n);
    k_scan2<<<1, 1024, 0, stream>>>(bsums, nb);
    k_scan3<<<(n + tb - 1) / tb, tb, 0, stream>>>(rowstart, bsums, n, etot);
    k_prep<<<1, 64, 0, stream>>>(W2, as2, ad2, rowstart, n, va, vd, gcnt);
    k_passA<<<(etot + ACHUNK - 1) / ACHUNK, 256, 0, stream>>>(eraw, e, etot, flag, n, pairs, gcnt);
    k_passB<<<1536, 256, 0, stream>>>(pairs, rowstart, n, cursor, csr);

    const int nodeBlocks4 = (n + 3) / 4;
    const int gemmBlocks = 1024;  // grid-stride; W regs amortized ~25 nodes/wave
    float* Xact = (float*)d_out;  // f32 X1 activations, later Agg, finally output

    // layer 0
    k_feat0<<<nodeBlocks4, 256, 0, stream>>>(x, W0, as0, ad0, Hbf, asn, adn, n);
    k_edge<4, 0><<<nodeBlocks4, 256, 0, stream>>>(Hbf, asn, adn, rowstart, csr, b0,
                                                  (float4*)Xact, nullptr, nullptr, nullptr,
                                                  nullptr, nullptr, n);
    // layer 1 (k_edge also emits layer-2 alpha dots into asn2/adn2)
    k_feat64<<<gemmBlocks, 256, 0, stream>>>(Xact, W1, as1, ad1, Hbf, asn, adn, n);
    k_edge<4, 1><<<nodeBlocks4, 256, 0, stream>>>(Hbf, asn, adn, rowstart, csr, b1,
                                                  nullptr, Xb2, va, vd, asn2, adn2, n);
    // layer 2 (linearity): aggregate Xb2 -> Agg(d_out); dense in-place
    k_edge<1, 2><<<nodeBlocks4, 256, 0, stream>>>(Xb2, asn2, adn2, rowstart, csr, nullptr,
                                                  (float4*)Xact, nullptr, nullptr, nullptr,
                                                  nullptr, nullptr, n);
    k_out<<<gemmBlocks, 256, 0, stream>>>(Xact, W2, b2, (float*)d_out, n);
}

// Round 10
// 423.093 us; speedup vs baseline: 2.2621x; 1.1904x over previous
//
#include <hip/hip_runtime.h>
#include <hip/hip_bf16.h>

// ---------------------------------------------------------------------------
// GAT encoder: 3 GATConv layers, N=100K nodes, E=1.6M edges (+N self loops).
// f32 inputs/outputs, int32 edges (int64 fallback via on-device flag).
// R10: dense 64x64 GEMMs (k_feat64, k_out) rewritten as blocked-LDS kernels:
//   W staged once per block (grid-stride, ~50 nodes/block amortizes it);
//   each wave processes 4 nodes/iter with X rows staged transposed in LDS:
//   per k: 1 conflict-free b32 W read + 1 b128 same-addr broadcast + 4 FMA.
//   No shfl, no per-node W reloads (R8/R9: compiler refused register-resident
//   W -> L2-BW bound 86us each; VGPR stuck at 64 despite launch_bounds).
// ---------------------------------------------------------------------------

#define LRELU(x, a) fmaxf((x), (a) * (x))
typedef unsigned int u32;
typedef unsigned short u16;

__device__ __forceinline__ float bf2f(u16 v) { return __uint_as_float(((u32)v) << 16); }
__device__ __forceinline__ u16 f2bf(float f) {
    u32 u = __float_as_uint(f);
    return (u16)((u + 0x7FFF + ((u >> 16) & 1)) >> 16);  // RNE, finite data
}

// flag: 0 => int64 (all sampled high words zero), 1 => int32
__global__ __launch_bounds__(1024) void k_detect(const int* __restrict__ eraw, int e,
                                                 int* __restrict__ flag) {
    int i = threadIdx.x;
    long long step = (long long)e / 1024;
    if (step == 0) step = 1;
    long long pos = 2LL * (i * step) + 1;
    if (pos < 2LL * e && eraw[pos] != 0) atomicExch(flag, 1);
}

__global__ __launch_bounds__(256) void k_hist(const int* __restrict__ eraw, int e, int etot,
                                              const int* __restrict__ flag,
                                              int* __restrict__ deg) {
    int i = blockIdx.x * blockDim.x + threadIdx.x;
    if (i >= etot) return;
    int d;
    if (i < e) d = (*flag == 0) ? eraw[2 * (e + i)] : eraw[e + i];
    else d = i - e;
    atomicAdd(&deg[d], 1);
}

__global__ __launch_bounds__(1024) void k_scan1(const int* __restrict__ deg,
                                                int* __restrict__ rowstart,
                                                int* __restrict__ bsums, int n) {
    __shared__ int sm[1024];
    int i = blockIdx.x * 1024 + threadIdx.x;
    int v = (i < n) ? deg[i] : 0;
    sm[threadIdx.x] = v;
    __syncthreads();
    for (int o = 1; o < 1024; o <<= 1) {
        int t = (threadIdx.x >= o) ? sm[threadIdx.x - o] : 0;
        __syncthreads();
        sm[threadIdx.x] += t;
        __syncthreads();
    }
    if (i < n) rowstart[i] = sm[threadIdx.x] - v;  // exclusive
    if (threadIdx.x == 1023) bsums[blockIdx.x] = sm[1023];
}

__global__ __launch_bounds__(1024) void k_scan2(int* __restrict__ bsums, int nb) {
    __shared__ int sm[1024];
    int v = (threadIdx.x < nb) ? bsums[threadIdx.x] : 0;
    sm[threadIdx.x] = v;
    __syncthreads();
    for (int o = 1; o < 1024; o <<= 1) {
        int t = (threadIdx.x >= o) ? sm[threadIdx.x - o] : 0;
        __syncthreads();
        sm[threadIdx.x] += t;
        __syncthreads();
    }
    if (threadIdx.x < nb) bsums[threadIdx.x] = sm[threadIdx.x] - v;  // exclusive
}

__global__ __launch_bounds__(256) void k_scan3(int* __restrict__ rowstart,
                                               const int* __restrict__ bsums, int n, int etot) {
    int i = blockIdx.x * blockDim.x + threadIdx.x;
    if (i < n) rowstart[i] += bsums[i >> 10];
    if (i == 0) rowstart[n] = etot;
}

// va = W2 @ as2, vd = W2 @ ad2; also init per-bucket pair cursors from rowstart
__global__ __launch_bounds__(64) void k_prep(const float* __restrict__ W2,
                                             const float* __restrict__ as2,
                                             const float* __restrict__ ad2,
                                             const int* __restrict__ rowstart, int n,
                                             float* __restrict__ va, float* __restrict__ vd,
                                             int* __restrict__ gcnt) {
    int k = threadIdx.x;
    float sa = 0.f, sd = 0.f;
    for (int j = 0; j < 64; j++) {
        float w = W2[k * 64 + j];
        sa += w * as2[j];
        sd += w * ad2[j];
    }
    va[k] = sa;
    vd[k] = sd;
    if (k < 8) gcnt[k] = rowstart[(k * n + 7) / 8];
}

// Pass A: append (s,d) into dense per-bucket streams (bucket = dst range).
#define ACHUNK 2048
__global__ __launch_bounds__(256) void k_passA(const int* __restrict__ eraw, int e, int etot,
                                               const int* __restrict__ flag, int n,
                                               int2* __restrict__ pairs, int* __restrict__ gcnt) {
    __shared__ int cnt[8];
    if (threadIdx.x < 8) cnt[threadIdx.x] = 0;
    __syncthreads();
    const int base = blockIdx.x * ACHUNK;
    const bool i64 = (*flag == 0);
    int s_[8], d_[8], b_[8];
    #pragma unroll
    for (int j = 0; j < 8; j++) {
        int i = base + j * 256 + threadIdx.x;
        if (i < etot) {
            int s, d;
            if (i < e) {
                if (i64) { s = eraw[2 * i]; d = eraw[2 * (e + i)]; }
                else     { s = eraw[i];     d = eraw[e + i]; }
            } else { s = i - e; d = i - e; }
            s_[j] = s; d_[j] = d;
            int b = (int)(((long long)d * 8) / n);
            b_[j] = b;
            atomicAdd(&cnt[b], 1);
        } else b_[j] = -1;
    }
    __syncthreads();
    if (threadIdx.x < 8) cnt[threadIdx.x] = atomicAdd(&gcnt[threadIdx.x], cnt[threadIdx.x]);
    __syncthreads();
    #pragma unroll
    for (int j = 0; j < 8; j++) {
        if (b_[j] >= 0) {
            int slot = atomicAdd(&cnt[b_[j]], 1);  // cnt now holds absolute offsets
            pairs[slot] = make_int2(s_[j], d_[j]);
        }
    }
}

// Pass B: bucket b processed by blocks with blockIdx%8==b (XCD round-robin
// heuristic -> csr/cursor writes stay in one XCD's L2). Perf-only assumption.
__global__ __launch_bounds__(256) void k_passB(const int2* __restrict__ pairs,
                                               const int* __restrict__ rowstart, int n,
                                               int* __restrict__ cursor, int* __restrict__ csr) {
    const int b = blockIdx.x & 7;
    const int sub = blockIdx.x >> 3;
    const int NSUB = gridDim.x >> 3;
    const int rb = rowstart[(b * n + 7) / 8];
    const int re = rowstart[((b + 1) * n + 7) / 8];
    const int len = re - rb;
    const int per = (len + NSUB - 1) / NSUB;
    const int lo = rb + sub * per;
    const int hi = min(lo + per, re);
    for (int i = lo + (int)threadIdx.x; i < hi; i += 256) {
        int2 p = pairs[i];
        int pos = rowstart[p.y] + atomicAdd(&cursor[p.y], 1);
        csr[pos] = p.x;
    }
}

// layer 0: h = x[N,2] @ W[2,64]; per-head (4x16) alpha dots -> bf16 H.
__global__ __launch_bounds__(256) void k_feat0(const float* __restrict__ Xin,
                                               const float* __restrict__ W,
                                               const float* __restrict__ Asrc,
                                               const float* __restrict__ Adst,
                                               u16* __restrict__ Hb, float* __restrict__ asn,
                                               float* __restrict__ adn, int n) {
    const int wv = threadIdx.x >> 6, ln = threadIdx.x & 63;
    const float w0 = W[ln], w1 = W[64 + ln];
    const float a_s = Asrc[ln], a_d = Adst[ln];
    for (int node = blockIdx.x * 4 + wv; node < n; node += gridDim.x * 4) {
        float x0 = Xin[node * 2 + 0], x1 = Xin[node * 2 + 1];
        float acc = fmaf(x1, w1, x0 * w0);
        float ts = acc * a_s, td = acc * a_d;
        #pragma unroll
        for (int o = 1; o < 16; o <<= 1) {
            ts += __shfl_xor(ts, o, 16);
            td += __shfl_xor(td, o, 16);
        }
        Hb[node * 64 + ln] = f2bf(acc);
        if ((ln & 15) == 0) {
            asn[node * 4 + (ln >> 4)] = ts;
            adn[node * 4 + (ln >> 4)] = td;
        }
    }
}

// layer 1: h = X[N,64](f32) @ W[64,64] -> bf16 H + per-head alpha dots.
// Blocked: W in LDS (staged once/block); wave does 4 nodes/iter, X transposed
// in wave-private LDS; per k: b32 W (conflict-free) + b128 broadcast + 4 FMA.
__global__ __launch_bounds__(256) void k_feat64(const float* __restrict__ Xin,
                                                const float* __restrict__ W,
                                                const float* __restrict__ Asrc,
                                                const float* __restrict__ Adst,
                                                u16* __restrict__ Hb, float* __restrict__ asn,
                                                float* __restrict__ adn, int n) {
    __shared__ float Ws[64 * 64];
    __shared__ __align__(16) float Xs[4][256];  // [wave][k*4 + nodeslot]
    for (int i = threadIdx.x; i < 64 * 64; i += 256) Ws[i] = W[i];
    __syncthreads();
    const int wv = threadIdx.x >> 6, ln = threadIdx.x & 63;
    const float a_s = Asrc[ln], a_d = Adst[ln];
    const int r = ln >> 4;         // node slot 0..3 (staging)
    const int c4 = (ln & 15) * 4;  // k-quad (staging)
    for (int g0 = blockIdx.x * 16 + wv * 4; g0 < n; g0 += gridDim.x * 16) {
        int node_r = g0 + r;
        float4 xq = (node_r < n) ? *(const float4*)&Xin[(size_t)node_r * 64 + c4]
                                 : make_float4(0.f, 0.f, 0.f, 0.f);
        Xs[wv][(c4 + 0) * 4 + r] = xq.x;
        Xs[wv][(c4 + 1) * 4 + r] = xq.y;
        Xs[wv][(c4 + 2) * 4 + r] = xq.z;
        Xs[wv][(c4 + 3) * 4 + r] = xq.w;   // wave-private; dep via lgkmcnt
        float acc0 = 0.f, acc1 = 0.f, acc2 = 0.f, acc3 = 0.f;
        #pragma unroll 8
        for (int k = 0; k < 64; k++) {
            float w = Ws[k * 64 + ln];
            float4 xk = *(const float4*)&Xs[wv][k * 4];
            acc0 = fmaf(xk.x, w, acc0);
            acc1 = fmaf(xk.y, w, acc1);
            acc2 = fmaf(xk.z, w, acc2);
            acc3 = fmaf(xk.w, w, acc3);
        }
        #pragma unroll
        for (int j = 0; j < 4; j++) {
            int node = g0 + j;
            if (node >= n) break;
            float acc = (j == 0) ? acc0 : (j == 1) ? acc1 : (j == 2) ? acc2 : acc3;
            float ts = acc * a_s, td = acc * a_d;
            #pragma unroll
            for (int o = 1; o < 16; o <<= 1) {
                ts += __shfl_xor(ts, o, 16);
                td += __shfl_xor(td, o, 16);
            }
            Hb[(size_t)node * 64 + ln] = f2bf(acc);
            if ((ln & 15) == 0) {
                asn[node * 4 + (ln >> 4)] = ts;
                adn[node * 4 + (ln >> 4)] = td;
            }
        }
    }
}

// Fused segment softmax + aggregation, one wave per dst node, bf16 H gather.
// 8 edges in flight: 8-lane group g handles edges start+g, +8, ...; lane q
// owns channels 8q..8q+7 (one uint4 = 8 bf16).
// OUTMODE 0: f32 out = leaky(acc/sum + bias, 0.01)   (layer-0 -> X1 in d_out)
// OUTMODE 1: bf16 out = leaky(acc/sum + bias, 0.01)  (layer-1 -> Xb2)
//            + fused layer-2 alpha dots (va/vd) -> asn2/adn2
// OUTMODE 2: f32 out = acc/sum                       (layer-2 aggregation)
template <int HEADS, int OUTMODE>
__global__ __launch_bounds__(256) void k_edge(const u16* __restrict__ Hb,
                                              const float* __restrict__ asn,
                                              const float* __restrict__ adn,
                                              const int* __restrict__ rowstart,
                                              const int* __restrict__ csr,
                                              const float* __restrict__ bias,
                                              float4* __restrict__ Outf,
                                              u16* __restrict__ Outb,
                                              const float* __restrict__ va,
                                              const float* __restrict__ vd,
                                              float* __restrict__ asn2,
                                              float* __restrict__ adn2, int n) {
    const int wv = threadIdx.x >> 6, ln = threadIdx.x & 63;
    const int node = blockIdx.x * 4 + wv;
    if (node >= n) return;
    const int g = ln >> 3, q = ln & 7;
    const int head = (HEADS == 4) ? (q >> 1) : 0;
    const int start = rowstart[node], end = rowstart[node + 1];
    const float adme = adn[node * HEADS + head];

    float a0 = 0.f, a1 = 0.f, a2 = 0.f, a3 = 0.f, a4 = 0.f, a5 = 0.f, a6 = 0.f, a7 = 0.f;
    float sw = 0.f;
    for (int eg = start + g; eg < end; eg += 8) {
        int s = csr[eg];
        float l = LRELU(asn[s * HEADS + head] + adme, 0.2f);
        float w = __expf(l);
        sw += w;
        uint4 hv = ((const uint4*)Hb)[s * 8 + q];
        a0 = fmaf(w, bf2f((u16)(hv.x & 0xffff)), a0);
        a1 = fmaf(w, bf2f((u16)(hv.x >> 16)), a1);
        a2 = fmaf(w, bf2f((u16)(hv.y & 0xffff)), a2);
        a3 = fmaf(w, bf2f((u16)(hv.y >> 16)), a3);
        a4 = fmaf(w, bf2f((u16)(hv.z & 0xffff)), a4);
        a5 = fmaf(w, bf2f((u16)(hv.z >> 16)), a5);
        a6 = fmaf(w, bf2f((u16)(hv.w & 0xffff)), a6);
        a7 = fmaf(w, bf2f((u16)(hv.w >> 16)), a7);
    }
    #pragma unroll
    for (int o = 8; o < 64; o <<= 1) {
        a0 += __shfl_xor(a0, o); a1 += __shfl_xor(a1, o);
        a2 += __shfl_xor(a2, o); a3 += __shfl_xor(a3, o);
        a4 += __shfl_xor(a4, o); a5 += __shfl_xor(a5, o);
        a6 += __shfl_xor(a6, o); a7 += __shfl_xor(a7, o);
        sw += __shfl_xor(sw, o);
    }
    if (ln < 8) {
        const float inv = 1.0f / sw;
        float r0 = a0 * inv, r1 = a1 * inv, r2 = a2 * inv, r3 = a3 * inv;
        float r4 = a4 * inv, r5 = a5 * inv, r6 = a6 * inv, r7 = a7 * inv;
        if constexpr (OUTMODE != 2) {
            const float4 bA = ((const float4*)bias)[2 * q];
            const float4 bB = ((const float4*)bias)[2 * q + 1];
            r0 = LRELU(r0 + bA.x, 0.01f); r1 = LRELU(r1 + bA.y, 0.01f);
            r2 = LRELU(r2 + bA.z, 0.01f); r3 = LRELU(r3 + bA.w, 0.01f);
            r4 = LRELU(r4 + bB.x, 0.01f); r5 = LRELU(r5 + bB.y, 0.01f);
            r6 = LRELU(r6 + bB.z, 0.01f); r7 = LRELU(r7 + bB.w, 0.01f);
        }
        if constexpr (OUTMODE == 1) {
            uint4 pb;
            pb.x = (u32)f2bf(r0) | ((u32)f2bf(r1) << 16);
            pb.y = (u32)f2bf(r2) | ((u32)f2bf(r3) << 16);
            pb.z = (u32)f2bf(r4) | ((u32)f2bf(r5) << 16);
            pb.w = (u32)f2bf(r6) | ((u32)f2bf(r7) << 16);
            ((uint4*)Outb)[node * 8 + q] = pb;
            // fused layer-2 alpha dots: asn2[node] = X2row.va, adn2[node] = X2row.vd
            const float4 vA = ((const float4*)va)[2 * q];
            const float4 vB = ((const float4*)va)[2 * q + 1];
            const float4 dA = ((const float4*)vd)[2 * q];
            const float4 dB = ((const float4*)vd)[2 * q + 1];
            float ts = r0 * vA.x + r1 * vA.y + r2 * vA.z + r3 * vA.w +
                       r4 * vB.x + r5 * vB.y + r6 * vB.z + r7 * vB.w;
            float td = r0 * dA.x + r1 * dA.y + r2 * dA.z + r3 * dA.w +
                       r4 * dB.x + r5 * dB.y + r6 * dB.z + r7 * dB.w;
            ts += __shfl_xor(ts, 1, 8); td += __shfl_xor(td, 1, 8);
            ts += __shfl_xor(ts, 2, 8); td += __shfl_xor(td, 2, 8);
            ts += __shfl_xor(ts, 4, 8); td += __shfl_xor(td, 4, 8);
            if (ln == 0) { asn2[node] = ts; adn2[node] = td; }
        } else {
            float4 oA = make_float4(r0, r1, r2, r3);
            float4 oB = make_float4(r4, r5, r6, r7);
            Outf[node * 16 + 2 * q] = oA;
            Outf[node * 16 + 2 * q + 1] = oB;
        }
    }
}

// final dense: out = Agg[N,64] @ W2 + b2. Blocked-LDS like k_feat64.
// In-place on d_out: each wave reads its 4 rows fully before writing them.
__global__ __launch_bounds__(256) void k_out(const float* __restrict__ Agg,
                                             const float* __restrict__ W2,
                                             const float* __restrict__ b2,
                                             float* __restrict__ Out, int n) {
    __shared__ float Ws[64 * 64];
    __shared__ __align__(16) float Xs[4][256];
    for (int i = threadIdx.x; i < 64 * 64; i += 256) Ws[i] = W2[i];
    __syncthreads();
    const int wv = threadIdx.x >> 6, ln = threadIdx.x & 63;
    const float bb = b2[ln];
    const int r = ln >> 4;
    const int c4 = (ln & 15) * 4;
    for (int g0 = blockIdx.x * 16 + wv * 4; g0 < n; g0 += gridDim.x * 16) {
        int node_r = g0 + r;
        float4 xq = (node_r < n) ? *(const float4*)&Agg[(size_t)node_r * 64 + c4]
                                 : make_float4(0.f, 0.f, 0.f, 0.f);
        Xs[wv][(c4 + 0) * 4 + r] = xq.x;
        Xs[wv][(c4 + 1) * 4 + r] = xq.y;
        Xs[wv][(c4 + 2) * 4 + r] = xq.z;
        Xs[wv][(c4 + 3) * 4 + r] = xq.w;
        float acc0 = 0.f, acc1 = 0.f, acc2 = 0.f, acc3 = 0.f;
        #pragma unroll 8
        for (int k = 0; k < 64; k++) {
            float w = Ws[k * 64 + ln];
            float4 xk = *(const float4*)&Xs[wv][k * 4];
            acc0 = fmaf(xk.x, w, acc0);
            acc1 = fmaf(xk.y, w, acc1);
            acc2 = fmaf(xk.z, w, acc2);
            acc3 = fmaf(xk.w, w, acc3);
        }
        #pragma unroll
        for (int j = 0; j < 4; j++) {
            int node = g0 + j;
            if (node >= n) break;
            float acc = (j == 0) ? acc0 : (j == 1) ? acc1 : (j == 2) ? acc2 : acc3;
            Out[(size_t)node * 64 + ln] = acc + bb;
        }
    }
}

extern "C" void kernel_launch(void* const* d_in, const int* in_sizes, int n_in, void* d_out,
                              int out_size, void* d_ws, size_t ws_size, hipStream_t stream) {
    const float* x = (const float*)d_in[0];
    const int* eraw = (const int*)d_in[1];
    const float* W0 = (const float*)d_in[2];
    const float* as0 = (const float*)d_in[3];
    const float* ad0 = (const float*)d_in[4];
    const float* b0 = (const float*)d_in[5];
    const float* W1 = (const float*)d_in[6];
    const float* as1 = (const float*)d_in[7];
    const float* ad1 = (const float*)d_in[8];
    const float* b1 = (const float*)d_in[9];
    const float* W2 = (const float*)d_in[10];
    const float* as2 = (const float*)d_in[11];
    const float* ad2 = (const float*)d_in[12];
    const float* b2 = (const float*)d_in[13];

    const int n = in_sizes[0] / 2;   // x [N,2]
    const int e = in_sizes[1] / 2;   // edge_index [2,E]
    const int etot = e + n;

    char* wp = (char*)d_ws;
    size_t off = 0;
    auto take = [&](size_t bytes) -> void* {
        void* p = wp + off;
        off = (off + bytes + 255) & ~(size_t)255;
        return p;
    };
    // union region: Hbf (bf16 N*64) + Xb2 (bf16 N*64) overlap pairs (int2*etot)
    size_t hsz = (size_t)n * 64 * 2;
    size_t usz = 2 * hsz > (size_t)etot * 8 ? 2 * hsz : (size_t)etot * 8;
    char* ubase   = (char*)take(usz);
    u16* Hbf      = (u16*)ubase;
    u16* Xb2      = (u16*)(ubase + hsz);
    int2* pairs   = (int2*)ubase;              // dead before Hbf/Xb2 are written
    float* asn    = (float*)take((size_t)n * 4 * 4);
    float* adn    = (float*)take((size_t)n * 4 * 4);
    float* asn2   = (float*)take((size_t)n * 4);
    float* adn2   = (float*)take((size_t)n * 4);
    int* deg      = (int*)take((size_t)2 * n * 4);   // deg + cursor
    int* cursor   = deg + n;
    int* rowstart = (int*)take((size_t)(n + 1) * 4);
    int* bsums    = (int*)take(1024 * 4);
    int* flag     = (int*)take(256);
    float* va     = (float*)take(64 * 4);
    float* vd     = (float*)take(64 * 4);
    int* gcnt     = (int*)take(256);
    int* csr      = (int*)take((size_t)etot * 4);
    (void)ws_size;

    hipMemsetAsync(deg, 0, (size_t)2 * n * 4, stream);
    hipMemsetAsync(flag, 0, 4, stream);

    const int tb = 256;
    k_detect<<<1, 1024, 0, stream>>>(eraw, e, flag);
    k_hist<<<(etot + tb - 1) / tb, tb, 0, stream>>>(eraw, e, etot, flag, deg);
    const int nb = (n + 1023) / 1024;
    k_scan1<<<nb, 1024, 0, stream>>>(deg, rowstart, bsums, n);
    k_scan2<<<1, 1024, 0, stream>>>(bsums, nb);
    k_scan3<<<(n + tb - 1) / tb, tb, 0, stream>>>(rowstart, bsums, n, etot);
    k_prep<<<1, 64, 0, stream>>>(W2, as2, ad2, rowstart, n, va, vd, gcnt);
    k_passA<<<(etot + ACHUNK - 1) / ACHUNK, 256, 0, stream>>>(eraw, e, etot, flag, n, pairs, gcnt);
    k_passB<<<1536, 256, 0, stream>>>(pairs, rowstart, n, cursor, csr);

    const int nodeBlocks4 = (n + 3) / 4;
    const int gemmBlocks = 2048;  // grid-stride; W staged once per block (~49 nodes)
    float* Xact = (float*)d_out;  // f32 X1 activations, later Agg, finally output

    // layer 0
    k_feat0<<<nodeBlocks4, 256, 0, stream>>>(x, W0, as0, ad0, Hbf, asn, adn, n);
    k_edge<4, 0><<<nodeBlocks4, 256, 0, stream>>>(Hbf, asn, adn, rowstart, csr, b0,
                                                  (float4*)Xact, nullptr, nullptr, nullptr,
                                                  nullptr, nullptr, n);
    // layer 1 (k_edge also emits layer-2 alpha dots into asn2/adn2)
    k_feat64<<<gemmBlocks, 256, 0, stream>>>(Xact, W1, as1, ad1, Hbf, asn, adn, n);
    k_edge<4, 1><<<nodeBlocks4, 256, 0, stream>>>(Hbf, asn, adn, rowstart, csr, b1,
                                                  nullptr, Xb2, va, vd, asn2, adn2, n);
    // layer 2 (linearity): aggregate Xb2 -> Agg(d_out); dense in-place
    k_edge<1, 2><<<nodeBlocks4, 256, 0, stream>>>(Xb2, asn2, adn2, rowstart, csr, nullptr,
                                                  (float4*)Xact, nullptr, nullptr, nullptr,
                                                  nullptr, nullptr, n);
    k_out<<<gemmBlocks, 256, 0, stream>>>(Xact, W2, b2, (float*)d_out, n);
}

// Round 12
// 309.264 us; speedup vs baseline: 3.0947x; 1.3681x over previous
//
#include <hip/hip_runtime.h>
#include <hip/hip_bf16.h>

// ---------------------------------------------------------------------------
// GAT encoder: 3 GATConv layers, N=100K nodes, E=1.6M edges (+N self loops).
// f32 inputs/outputs, int32 edges (int64 fallback via on-device flag).
// R12: R11's 256-bucket LDS counting-sort CSR build with the bucket-boundary
// fix: passB node range is now node_lo(b)=ceil(b*n/NBUCKET) — the exact
// inverse of passA's bucket(d)=floor(d*NBUCKET/n). R11 used floor on both
// sides -> boundary nodes (e.g. 390) landed in bucket b-1's stream but were
// claimed by block b -> empty rowstart range -> 0*inf = NaN.
// ---------------------------------------------------------------------------

#define LRELU(x, a) fmaxf((x), (a) * (x))
typedef unsigned int u32;
typedef unsigned short u16;

#define NBUCKET 256
#define CAP_A 12288
#define OVCAP 65536

__device__ __forceinline__ float bf2f(u16 v) { return __uint_as_float(((u32)v) << 16); }
__device__ __forceinline__ u16 f2bf(float f) {
    u32 u = __float_as_uint(f);
    return (u16)((u + 0x7FFF + ((u >> 16) & 1)) >> 16);  // RNE, finite data
}

// flag: 0 => int64 (all sampled high words zero), 1 => int32
__global__ __launch_bounds__(1024) void k_detect(const int* __restrict__ eraw, int e,
                                                 int* __restrict__ flag) {
    int i = threadIdx.x;
    long long step = (long long)e / 1024;
    if (step == 0) step = 1;
    long long pos = 2LL * (i * step) + 1;
    if (pos < 2LL * e && eraw[pos] != 0) atomicExch(flag, 1);
}

// va = W2 @ as2, vd = W2 @ ad2
__global__ __launch_bounds__(64) void k_prep(const float* __restrict__ W2,
                                             const float* __restrict__ as2,
                                             const float* __restrict__ ad2,
                                             float* __restrict__ va, float* __restrict__ vd) {
    int k = threadIdx.x;
    float sa = 0.f, sd = 0.f;
    for (int j = 0; j < 64; j++) {
        float w = W2[k * 64 + j];
        sa += w * as2[j];
        sd += w * ad2[j];
    }
    va[k] = sa;
    vd[k] = sd;
}

// Pass A: append (s,d) into fixed-stride per-bucket streams (bucket = dst range).
#define ACHUNK 2048
__global__ __launch_bounds__(256) void k_passA(const int* __restrict__ eraw, int e, int etot,
                                               const int* __restrict__ flag, int n,
                                               int2* __restrict__ pairs, int* __restrict__ gcnt,
                                               int2* __restrict__ ovp, int* __restrict__ ovcnt) {
    __shared__ int bcnt[NBUCKET];
    if (threadIdx.x < NBUCKET) bcnt[threadIdx.x] = 0;
    __syncthreads();
    const int base = blockIdx.x * ACHUNK;
    const bool i64 = (*flag == 0);
    int s_[8], d_[8], b_[8];
    #pragma unroll
    for (int j = 0; j < 8; j++) {
        int i = base + j * 256 + threadIdx.x;
        if (i < etot) {
            int s, d;
            if (i < e) {
                if (i64) { s = eraw[2 * i]; d = eraw[2 * (e + i)]; }
                else     { s = eraw[i];     d = eraw[e + i]; }
            } else { s = i - e; d = i - e; }
            s_[j] = s; d_[j] = d;
            int b = (int)(((long long)d * NBUCKET) / n);
            b_[j] = b;
            atomicAdd(&bcnt[b], 1);
        } else b_[j] = -1;
    }
    __syncthreads();
    if (threadIdx.x < NBUCKET) {
        int c = bcnt[threadIdx.x];
        bcnt[threadIdx.x] = (c > 0) ? atomicAdd(&gcnt[threadIdx.x], c) : 0;
    }
    __syncthreads();
    #pragma unroll
    for (int j = 0; j < 8; j++) {
        if (b_[j] >= 0) {
            int slot = atomicAdd(&bcnt[b_[j]], 1);
            if (slot < CAP_A) {
                pairs[(size_t)b_[j] * CAP_A + slot] = make_int2(s_[j], d_[j]);
            } else {
                int ov = atomicAdd(ovcnt, 1);
                if (ov < OVCAP) ovp[ov] = make_int2(s_[j], d_[j]);
            }
        }
    }
}

// Pass B: one WG per bucket. LDS histogram + scan + scatter; streaming writes.
// Node range = EXACT inverse of passA's bucket function (ceil division).
__global__ __launch_bounds__(256) void k_passB(const int2* __restrict__ pairs,
                                               const int* __restrict__ gcnt,
                                               const int2* __restrict__ ovp,
                                               const int* __restrict__ ovcnt, int n, int etot,
                                               int* __restrict__ rowstart,
                                               int* __restrict__ csr) {
    __shared__ int lcsr[CAP_A];
    __shared__ int lscan[512];   // inclusive scan of local degrees
    __shared__ int lcur[512];    // scatter cursors (exclusive offsets)
    __shared__ int gscan[NBUCKET];
    const int b = blockIdx.x;
    const int tid = threadIdx.x;
    // smallest d with bucket(d) == b is ceil(b*n/NBUCKET)
    const int node_lo = (int)(((long long)b * n + NBUCKET - 1) / NBUCKET);
    const int node_hi = (int)(((long long)(b + 1) * n + NBUCKET - 1) / NBUCKET);
    const int nodes = node_hi - node_lo;          // <= 391 < 512
    const int cnt_total = gcnt[b];                // includes overflowed
    const int stored = min(cnt_total, CAP_A);
    const int nov = min(*ovcnt, OVCAP);

    // bucket base = prefix of gcnt
    gscan[tid] = gcnt[tid];
    __syncthreads();
    #pragma unroll
    for (int o = 1; o < NBUCKET; o <<= 1) {
        int v = (tid >= o) ? gscan[tid - o] : 0;
        __syncthreads();
        gscan[tid] += v;
        __syncthreads();
    }
    const int bucket_base = (b == 0) ? 0 : gscan[b - 1];

    // local degree histogram
    lscan[tid] = 0; lscan[tid + 256] = 0;
    __syncthreads();
    for (int i = tid; i < stored; i += 256) {
        int d = pairs[(size_t)b * CAP_A + i].y;
        atomicAdd(&lscan[d - node_lo], 1);
    }
    for (int i = tid; i < nov; i += 256) {
        int d = ovp[i].y;
        if (d >= node_lo && d < node_hi) atomicAdd(&lscan[d - node_lo], 1);
    }
    __syncthreads();
    // inclusive scan over 512 entries (256 threads x 2)
    #pragma unroll
    for (int o = 1; o < 512; o <<= 1) {
        int i0 = tid, i1 = tid + 256;
        int v0 = (i0 >= o) ? lscan[i0 - o] : 0;
        int v1 = (i1 >= o) ? lscan[i1 - o] : 0;
        __syncthreads();
        lscan[i0] += v0; lscan[i1] += v1;
        __syncthreads();
    }
    // rowstart + cursors (exclusive offsets)
    #pragma unroll
    for (int t = 0; t < 2; t++) {
        int j = tid + t * 256;
        int excl = (j == 0) ? 0 : lscan[j - 1];
        lcur[j] = excl;
        if (j < nodes) rowstart[node_lo + j] = bucket_base + excl;
    }
    if (b == NBUCKET - 1 && tid == 0) rowstart[n] = etot;
    __syncthreads();
    // scatter into LDS csr
    for (int i = tid; i < stored; i += 256) {
        int2 p = pairs[(size_t)b * CAP_A + i];
        int slot = atomicAdd(&lcur[p.y - node_lo], 1);
        lcsr[slot] = p.x;
    }
    for (int i = tid; i < nov; i += 256) {
        int2 p = ovp[i];
        if (p.y >= node_lo && p.y < node_hi) {
            int slot = atomicAdd(&lcur[p.y - node_lo], 1);
            lcsr[slot] = p.x;
        }
    }
    __syncthreads();
    // streaming write-out
    for (int i = tid; i < cnt_total; i += 256) csr[bucket_base + i] = lcsr[i];
}

// layer 0: h = x[N,2] @ W[2,64]; per-head (4x16) alpha dots -> bf16 H.
__global__ __launch_bounds__(256) void k_feat0(const float* __restrict__ Xin,
                                               const float* __restrict__ W,
                                               const float* __restrict__ Asrc,
                                               const float* __restrict__ Adst,
                                               u16* __restrict__ Hb, float* __restrict__ asn,
                                               float* __restrict__ adn, int n) {
    const int wv = threadIdx.x >> 6, ln = threadIdx.x & 63;
    const float w0 = W[ln], w1 = W[64 + ln];
    const float a_s = Asrc[ln], a_d = Adst[ln];
    for (int node = blockIdx.x * 4 + wv; node < n; node += gridDim.x * 4) {
        float x0 = Xin[node * 2 + 0], x1 = Xin[node * 2 + 1];
        float acc = fmaf(x1, w1, x0 * w0);
        float ts = acc * a_s, td = acc * a_d;
        #pragma unroll
        for (int o = 1; o < 16; o <<= 1) {
            ts += __shfl_xor(ts, o, 16);
            td += __shfl_xor(td, o, 16);
        }
        Hb[node * 64 + ln] = f2bf(acc);
        if ((ln & 15) == 0) {
            asn[node * 4 + (ln >> 4)] = ts;
            adn[node * 4 + (ln >> 4)] = td;
        }
    }
}

// layer 1: h = X[N,64](f32) @ W[64,64] -> bf16 H + per-head alpha dots.
// Blocked: W in LDS (staged once/block); wave does 4 nodes/iter, X transposed
// in wave-private LDS; per k: b32 W (conflict-free) + b128 broadcast + 4 FMA.
__global__ __launch_bounds__(256) void k_feat64(const float* __restrict__ Xin,
                                                const float* __restrict__ W,
                                                const float* __restrict__ Asrc,
                                                const float* __restrict__ Adst,
                                                u16* __restrict__ Hb, float* __restrict__ asn,
                                                float* __restrict__ adn, int n) {
    __shared__ float Ws[64 * 64];
    __shared__ __align__(16) float Xs[4][256];  // [wave][k*4 + nodeslot]
    for (int i = threadIdx.x; i < 64 * 64; i += 256) Ws[i] = W[i];
    __syncthreads();
    const int wv = threadIdx.x >> 6, ln = threadIdx.x & 63;
    const float a_s = Asrc[ln], a_d = Adst[ln];
    const int r = ln >> 4;         // node slot 0..3 (staging)
    const int c4 = (ln & 15) * 4;  // k-quad (staging)
    for (int g0 = blockIdx.x * 16 + wv * 4; g0 < n; g0 += gridDim.x * 16) {
        int node_r = g0 + r;
        float4 xq = (node_r < n) ? *(const float4*)&Xin[(size_t)node_r * 64 + c4]
                                 : make_float4(0.f, 0.f, 0.f, 0.f);
        Xs[wv][(c4 + 0) * 4 + r] = xq.x;
        Xs[wv][(c4 + 1) * 4 + r] = xq.y;
        Xs[wv][(c4 + 2) * 4 + r] = xq.z;
        Xs[wv][(c4 + 3) * 4 + r] = xq.w;   // wave-private; dep via lgkmcnt
        float acc0 = 0.f, acc1 = 0.f, acc2 = 0.f, acc3 = 0.f;
        #pragma unroll 8
        for (int k = 0; k < 64; k++) {
            float w = Ws[k * 64 + ln];
            float4 xk = *(const float4*)&Xs[wv][k * 4];
            acc0 = fmaf(xk.x, w, acc0);
            acc1 = fmaf(xk.y, w, acc1);
            acc2 = fmaf(xk.z, w, acc2);
            acc3 = fmaf(xk.w, w, acc3);
        }
        #pragma unroll
        for (int j = 0; j < 4; j++) {
            int node = g0 + j;
            if (node >= n) break;
            float acc = (j == 0) ? acc0 : (j == 1) ? acc1 : (j == 2) ? acc2 : acc3;
            float ts = acc * a_s, td = acc * a_d;
            #pragma unroll
            for (int o = 1; o < 16; o <<= 1) {
                ts += __shfl_xor(ts, o, 16);
                td += __shfl_xor(td, o, 16);
            }
            Hb[(size_t)node * 64 + ln] = f2bf(acc);
            if ((ln & 15) == 0) {
                asn[node * 4 + (ln >> 4)] = ts;
                adn[node * 4 + (ln >> 4)] = td;
            }
        }
    }
}

// Fused segment softmax + aggregation, one wave per dst node, bf16 H gather.
// 8 edges in flight: 8-lane group g handles edges start+g, +8, ...; lane q
// owns channels 8q..8q+7 (one uint4 = 8 bf16).
// OUTMODE 0: f32 out = leaky(acc/sum + bias, 0.01)   (layer-0 -> X1 in d_out)
// OUTMODE 1: bf16 out = leaky(acc/sum + bias, 0.01)  (layer-1 -> Xb2)
//            + fused layer-2 alpha dots (va/vd) -> asn2/adn2
// OUTMODE 2: f32 out = acc/sum                       (layer-2 aggregation)
template <int HEADS, int OUTMODE>
__global__ __launch_bounds__(256) void k_edge(const u16* __restrict__ Hb,
                                              const float* __restrict__ asn,
                                              const float* __restrict__ adn,
                                              const int* __restrict__ rowstart,
                                              const int* __restrict__ csr,
                                              const float* __restrict__ bias,
                                              float4* __restrict__ Outf,
                                              u16* __restrict__ Outb,
                                              const float* __restrict__ va,
                                              const float* __restrict__ vd,
                                              float* __restrict__ asn2,
                                              float* __restrict__ adn2, int n) {
    const int wv = threadIdx.x >> 6, ln = threadIdx.x & 63;
    const int node = blockIdx.x * 4 + wv;
    if (node >= n) return;
    const int g = ln >> 3, q = ln & 7;
    const int head = (HEADS == 4) ? (q >> 1) : 0;
    const int start = rowstart[node], end = rowstart[node + 1];
    const float adme = adn[node * HEADS + head];

    float a0 = 0.f, a1 = 0.f, a2 = 0.f, a3 = 0.f, a4 = 0.f, a5 = 0.f, a6 = 0.f, a7 = 0.f;
    float sw = 0.f;
    for (int eg = start + g; eg < end; eg += 8) {
        int s = csr[eg];
        float l = LRELU(asn[s * HEADS + head] + adme, 0.2f);
        float w = __expf(l);
        sw += w;
        uint4 hv = ((const uint4*)Hb)[s * 8 + q];
        a0 = fmaf(w, bf2f((u16)(hv.x & 0xffff)), a0);
        a1 = fmaf(w, bf2f((u16)(hv.x >> 16)), a1);
        a2 = fmaf(w, bf2f((u16)(hv.y & 0xffff)), a2);
        a3 = fmaf(w, bf2f((u16)(hv.y >> 16)), a3);
        a4 = fmaf(w, bf2f((u16)(hv.z & 0xffff)), a4);
        a5 = fmaf(w, bf2f((u16)(hv.z >> 16)), a5);
        a6 = fmaf(w, bf2f((u16)(hv.w & 0xffff)), a6);
        a7 = fmaf(w, bf2f((u16)(hv.w >> 16)), a7);
    }
    #pragma unroll
    for (int o = 8; o < 64; o <<= 1) {
        a0 += __shfl_xor(a0, o); a1 += __shfl_xor(a1, o);
        a2 += __shfl_xor(a2, o); a3 += __shfl_xor(a3, o);
        a4 += __shfl_xor(a4, o); a5 += __shfl_xor(a5, o);
        a6 += __shfl_xor(a6, o); a7 += __shfl_xor(a7, o);
        sw += __shfl_xor(sw, o);
    }
    if (ln < 8) {
        const float inv = 1.0f / sw;
        float r0 = a0 * inv, r1 = a1 * inv, r2 = a2 * inv, r3 = a3 * inv;
        float r4 = a4 * inv, r5 = a5 * inv, r6 = a6 * inv, r7 = a7 * inv;
        if constexpr (OUTMODE != 2) {
            const float4 bA = ((const float4*)bias)[2 * q];
            const float4 bB = ((const float4*)bias)[2 * q + 1];
            r0 = LRELU(r0 + bA.x, 0.01f); r1 = LRELU(r1 + bA.y, 0.01f);
            r2 = LRELU(r2 + bA.z, 0.01f); r3 = LRELU(r3 + bA.w, 0.01f);
            r4 = LRELU(r4 + bB.x, 0.01f); r5 = LRELU(r5 + bB.y, 0.01f);
            r6 = LRELU(r6 + bB.z, 0.01f); r7 = LRELU(r7 + bB.w, 0.01f);
        }
        if constexpr (OUTMODE == 1) {
            uint4 pb;
            pb.x = (u32)f2bf(r0) | ((u32)f2bf(r1) << 16);
            pb.y = (u32)f2bf(r2) | ((u32)f2bf(r3) << 16);
            pb.z = (u32)f2bf(r4) | ((u32)f2bf(r5) << 16);
            pb.w = (u32)f2bf(r6) | ((u32)f2bf(r7) << 16);
            ((uint4*)Outb)[node * 8 + q] = pb;
            // fused layer-2 alpha dots: asn2[node] = X2row.va, adn2[node] = X2row.vd
            const float4 vA = ((const float4*)va)[2 * q];
            const float4 vB = ((const float4*)va)[2 * q + 1];
            const float4 dA = ((const float4*)vd)[2 * q];
            const float4 dB = ((const float4*)vd)[2 * q + 1];
            float ts = r0 * vA.x + r1 * vA.y + r2 * vA.z + r3 * vA.w +
                       r4 * vB.x + r5 * vB.y + r6 * vB.z + r7 * vB.w;
            float td = r0 * dA.x + r1 * dA.y + r2 * dA.z + r3 * dA.w +
                       r4 * dB.x + r5 * dB.y + r6 * dB.z + r7 * dB.w;
            ts += __shfl_xor(ts, 1, 8); td += __shfl_xor(td, 1, 8);
            ts += __shfl_xor(ts, 2, 8); td += __shfl_xor(td, 2, 8);
            ts += __shfl_xor(ts, 4, 8); td += __shfl_xor(td, 4, 8);
            if (ln == 0) { asn2[node] = ts; adn2[node] = td; }
        } else {
            float4 oA = make_float4(r0, r1, r2, r3);
            float4 oB = make_float4(r4, r5, r6, r7);
            Outf[node * 16 + 2 * q] = oA;
            Outf[node * 16 + 2 * q + 1] = oB;
        }
    }
}

// final dense: out = Agg[N,64] @ W2 + b2. Blocked-LDS like k_feat64.
// In-place on d_out: each wave reads its 4 rows fully before writing them.
__global__ __launch_bounds__(256) void k_out(const float* __restrict__ Agg,
                                             const float* __restrict__ W2,
                                             const float* __restrict__ b2,
                                             float* __restrict__ Out, int n) {
    __shared__ float Ws[64 * 64];
    __shared__ __align__(16) float Xs[4][256];
    for (int i = threadIdx.x; i < 64 * 64; i += 256) Ws[i] = W2[i];
    __syncthreads();
    const int wv = threadIdx.x >> 6, ln = threadIdx.x & 63;
    const float bb = b2[ln];
    const int r = ln >> 4;
    const int c4 = (ln & 15) * 4;
    for (int g0 = blockIdx.x * 16 + wv * 4; g0 < n; g0 += gridDim.x * 16) {
        int node_r = g0 + r;
        float4 xq = (node_r < n) ? *(const float4*)&Agg[(size_t)node_r * 64 + c4]
                                 : make_float4(0.f, 0.f, 0.f, 0.f);
        Xs[wv][(c4 + 0) * 4 + r] = xq.x;
        Xs[wv][(c4 + 1) * 4 + r] = xq.y;
        Xs[wv][(c4 + 2) * 4 + r] = xq.z;
        Xs[wv][(c4 + 3) * 4 + r] = xq.w;
        float acc0 = 0.f, acc1 = 0.f, acc2 = 0.f, acc3 = 0.f;
        #pragma unroll 8
        for (int k = 0; k < 64; k++) {
            float w = Ws[k * 64 + ln];
            float4 xk = *(const float4*)&Xs[wv][k * 4];
            acc0 = fmaf(xk.x, w, acc0);
            acc1 = fmaf(xk.y, w, acc1);
            acc2 = fmaf(xk.z, w, acc2);
            acc3 = fmaf(xk.w, w, acc3);
        }
        #pragma unroll
        for (int j = 0; j < 4; j++) {
            int node = g0 + j;
            if (node >= n) break;
            float acc = (j == 0) ? acc0 : (j == 1) ? acc1 : (j == 2) ? acc2 : acc3;
            Out[(size_t)node * 64 + ln] = acc + bb;
        }
    }
}

extern "C" void kernel_launch(void* const* d_in, const int* in_sizes, int n_in, void* d_out,
                              int out_size, void* d_ws, size_t ws_size, hipStream_t stream) {
    const float* x = (const float*)d_in[0];
    const int* eraw = (const int*)d_in[1];
    const float* W0 = (const float*)d_in[2];
    const float* as0 = (const float*)d_in[3];
    const float* ad0 = (const float*)d_in[4];
    const float* b0 = (const float*)d_in[5];
    const float* W1 = (const float*)d_in[6];
    const float* as1 = (const float*)d_in[7];
    const float* ad1 = (const float*)d_in[8];
    const float* b1 = (const float*)d_in[9];
    const float* W2 = (const float*)d_in[10];
    const float* as2 = (const float*)d_in[11];
    const float* ad2 = (const float*)d_in[12];
    const float* b2 = (const float*)d_in[13];

    const int n = in_sizes[0] / 2;   // x [N,2]
    const int e = in_sizes[1] / 2;   // edge_index [2,E]
    const int etot = e + n;

    char* wp = (char*)d_ws;
    size_t off = 0;
    auto take = [&](size_t bytes) -> void* {
        void* p = wp + off;
        off = (off + bytes + 255) & ~(size_t)255;
        return p;
    };
    // union region: Hbf (bf16 N*64) + Xb2 (bf16 N*64) overlap pairs (256*CAP_A*8)
    size_t hsz = (size_t)n * 64 * 2;
    size_t psz = (size_t)NBUCKET * CAP_A * 8;
    size_t usz = 2 * hsz > psz ? 2 * hsz : psz;
    char* ubase   = (char*)take(usz);
    u16* Hbf      = (u16*)ubase;
    u16* Xb2      = (u16*)(ubase + hsz);
    int2* pairs   = (int2*)ubase;              // dead before Hbf/Xb2 are written
    float* asn    = (float*)take((size_t)n * 4 * 4);
    float* adn    = (float*)take((size_t)n * 4 * 4);
    float* asn2   = (float*)take((size_t)n * 4);
    float* adn2   = (float*)take((size_t)n * 4);
    int* rowstart = (int*)take((size_t)(n + 1) * 4);
    int* gcnt     = (int*)take(NBUCKET * 4);
    int* flag     = (int*)take(256);           // flag + ovcnt
    int* ovcnt    = flag + 1;
    float* va     = (float*)take(64 * 4);
    float* vd     = (float*)take(64 * 4);
    int2* ovp     = (int2*)take((size_t)OVCAP * 8);
    int* csr      = (int*)take((size_t)etot * 4);
    (void)ws_size;

    hipMemsetAsync(gcnt, 0, NBUCKET * 4, stream);
    hipMemsetAsync(flag, 0, 256, stream);

    k_detect<<<1, 1024, 0, stream>>>(eraw, e, flag);
    k_prep<<<1, 64, 0, stream>>>(W2, as2, ad2, va, vd);
    k_passA<<<(etot + ACHUNK - 1) / ACHUNK, 256, 0, stream>>>(eraw, e, etot, flag, n, pairs,
                                                              gcnt, ovp, ovcnt);
    k_passB<<<NBUCKET, 256, 0, stream>>>(pairs, gcnt, ovp, ovcnt, n, etot, rowstart, csr);

    const int nodeBlocks4 = (n + 3) / 4;
    const int gemmBlocks = 2048;  // grid-stride; W staged once per block (~49 nodes)
    float* Xact = (float*)d_out;  // f32 X1 activations, later Agg, finally output

    // layer 0
    k_feat0<<<nodeBlocks4, 256, 0, stream>>>(x, W0, as0, ad0, Hbf, asn, adn, n);
    k_edge<4, 0><<<nodeBlocks4, 256, 0, stream>>>(Hbf, asn, adn, rowstart, csr, b0,
                                                  (float4*)Xact, nullptr, nullptr, nullptr,
                                                  nullptr, nullptr, n);
    // layer 1 (k_edge also emits layer-2 alpha dots into asn2/adn2)
    k_feat64<<<gemmBlocks, 256, 0, stream>>>(Xact, W1, as1, ad1, Hbf, asn, adn, n);
    k_edge<4, 1><<<nodeBlocks4, 256, 0, stream>>>(Hbf, asn, adn, rowstart, csr, b1,
                                                  nullptr, Xb2, va, vd, asn2, adn2, n);
    // layer 2 (linearity): aggregate Xb2 -> Agg(d_out); dense in-place
    k_edge<1, 2><<<nodeBlocks4, 256, 0, stream>>>(Xb2, asn2, adn2, rowstart, csr, nullptr,
                                                  (float4*)Xact, nullptr, nullptr, nullptr,
                                                  nullptr, nullptr, n);
    k_out<<<gemmBlocks, 256, 0, stream>>>(Xact, W2, b2, (float*)d_out, n);
}

// Round 15
// 289.956 us; speedup vs baseline: 3.3008x; 1.0666x over previous
//
#include <hip/hip_runtime.h>
#include <hip/hip_bf16.h>

// ---------------------------------------------------------------------------
// GAT encoder: 3 GATConv layers, N=100K nodes, E=1.6M edges (+N self loops).
// f32 inputs/outputs, int32 edges (int64 fallback via on-device flag).
// R15 = R14 with the macro-shadowing fix: EDGE_BODY's local was `int s=(SRC)`
// and R14 passed a variable NAMED s -> `int s = (s)` self-init (indeterminate)
// -> garbage gather indices for all main-loop edges (0.253 absmax). Local
// renamed s_e. (R13's separate bug was inactive-lane __shfl; its fix -- the
// wave-uniform trip count -- is retained unchanged.)
// ---------------------------------------------------------------------------

#define LRELU(x, a) fmaxf((x), (a) * (x))
typedef unsigned int u32;
typedef unsigned short u16;

#define NBUCKET 256
#define CAP_A 12288
#define OVCAP 65536

__device__ __forceinline__ float bf2f(u16 v) { return __uint_as_float(((u32)v) << 16); }
__device__ __forceinline__ u16 f2bf(float f) {
    u32 u = __float_as_uint(f);
    return (u16)((u + 0x7FFF + ((u >> 16) & 1)) >> 16);  // RNE, finite data
}

// merged: edge-dtype detect (flag: 0=>int64, 1=>int32) + va/vd precompute
__global__ __launch_bounds__(1024) void k_init(const int* __restrict__ eraw, int e,
                                               int* __restrict__ flag,
                                               const float* __restrict__ W2,
                                               const float* __restrict__ as2,
                                               const float* __restrict__ ad2,
                                               float* __restrict__ va, float* __restrict__ vd) {
    int i = threadIdx.x;
    long long step = (long long)e / 1024;
    if (step == 0) step = 1;
    long long pos = 2LL * (i * step) + 1;
    if (pos < 2LL * e && eraw[pos] != 0) atomicExch(flag, 1);
    if (i < 64) {
        float sa = 0.f, sd = 0.f;
        for (int j = 0; j < 64; j++) {
            float w = W2[i * 64 + j];
            sa += w * as2[j];
            sd += w * ad2[j];
        }
        va[i] = sa;
        vd[i] = sd;
    }
}

// Pass A: append compressed keys (s | dloc<<18) into fixed-stride bucket streams.
#define ACHUNK 2048
__global__ __launch_bounds__(256) void k_passA(const int* __restrict__ eraw, int e, int etot,
                                               const int* __restrict__ flag, int n,
                                               u32* __restrict__ keys, int* __restrict__ gcnt,
                                               int2* __restrict__ ovp, int* __restrict__ ovcnt) {
    __shared__ int bcnt[NBUCKET];
    bcnt[threadIdx.x] = 0;
    __syncthreads();
    const int base = blockIdx.x * ACHUNK;
    const bool i64 = (*flag == 0);
    int s_[8], d_[8], b_[8];
    u32 key_[8];
    #pragma unroll
    for (int j = 0; j < 8; j++) {
        int i = base + j * 256 + threadIdx.x;
        if (i < etot) {
            int s, d;
            if (i < e) {
                if (i64) { s = eraw[2 * i]; d = eraw[2 * (e + i)]; }
                else     { s = eraw[i];     d = eraw[e + i]; }
            } else { s = i - e; d = i - e; }
            s_[j] = s; d_[j] = d;
            int b = (int)(((long long)d * NBUCKET) / n);
            int node_lo_b = (int)(((long long)b * n + NBUCKET - 1) / NBUCKET);
            b_[j] = b;
            key_[j] = (u32)s | ((u32)(d - node_lo_b) << 18);
            atomicAdd(&bcnt[b], 1);
        } else b_[j] = -1;
    }
    __syncthreads();
    {
        int c = bcnt[threadIdx.x];
        bcnt[threadIdx.x] = (c > 0) ? atomicAdd(&gcnt[threadIdx.x], c) : 0;
    }
    __syncthreads();
    #pragma unroll
    for (int j = 0; j < 8; j++) {
        if (b_[j] >= 0) {
            int slot = atomicAdd(&bcnt[b_[j]], 1);
            if (slot < CAP_A) {
                keys[(size_t)b_[j] * CAP_A + slot] = key_[j];
            } else {
                int ov = atomicAdd(ovcnt, 1);
                if (ov < OVCAP) ovp[ov] = make_int2(s_[j], d_[j]);
            }
        }
    }
}

// Pass B: one WG per bucket. LDS histogram + scan + scatter; streaming writes.
// Node range = EXACT inverse of passA's bucket function (ceil division).
__global__ __launch_bounds__(256) void k_passB(const u32* __restrict__ keys,
                                               const int* __restrict__ gcnt,
                                               const int2* __restrict__ ovp,
                                               const int* __restrict__ ovcnt, int n, int etot,
                                               int* __restrict__ rowstart,
                                               int* __restrict__ csr) {
    __shared__ int lcsr[CAP_A];
    __shared__ int lscan[512];
    __shared__ int lcur[512];
    __shared__ int gscan[NBUCKET];
    const int b = blockIdx.x;
    const int tid = threadIdx.x;
    const int node_lo = (int)(((long long)b * n + NBUCKET - 1) / NBUCKET);
    const int node_hi = (int)(((long long)(b + 1) * n + NBUCKET - 1) / NBUCKET);
    const int nodes = node_hi - node_lo;          // <= 391 < 512
    const int cnt_total = gcnt[b];                // includes overflowed
    const int stored = min(cnt_total, CAP_A);
    const int nov = min(*ovcnt, OVCAP);

    gscan[tid] = gcnt[tid];
    __syncthreads();
    #pragma unroll
    for (int o = 1; o < NBUCKET; o <<= 1) {
        int v = (tid >= o) ? gscan[tid - o] : 0;
        __syncthreads();
        gscan[tid] += v;
        __syncthreads();
    }
    const int bucket_base = (b == 0) ? 0 : gscan[b - 1];

    lscan[tid] = 0; lscan[tid + 256] = 0;
    __syncthreads();
    for (int i = tid; i < stored; i += 256) {
        int dloc = keys[(size_t)b * CAP_A + i] >> 18;
        atomicAdd(&lscan[dloc], 1);
    }
    for (int i = tid; i < nov; i += 256) {
        int d = ovp[i].y;
        if (d >= node_lo && d < node_hi) atomicAdd(&lscan[d - node_lo], 1);
    }
    __syncthreads();
    #pragma unroll
    for (int o = 1; o < 512; o <<= 1) {
        int i0 = tid, i1 = tid + 256;
        int v0 = (i0 >= o) ? lscan[i0 - o] : 0;
        int v1 = (i1 >= o) ? lscan[i1 - o] : 0;
        __syncthreads();
        lscan[i0] += v0; lscan[i1] += v1;
        __syncthreads();
    }
    #pragma unroll
    for (int t = 0; t < 2; t++) {
        int j = tid + t * 256;
        int excl = (j == 0) ? 0 : lscan[j - 1];
        lcur[j] = excl;
        if (j < nodes) rowstart[node_lo + j] = bucket_base + excl;
    }
    if (b == NBUCKET - 1 && tid == 0) rowstart[n] = etot;
    __syncthreads();
    for (int i = tid; i < stored; i += 256) {
        u32 k = keys[(size_t)b * CAP_A + i];
        int slot = atomicAdd(&lcur[k >> 18], 1);
        lcsr[slot] = (int)(k & 0x3FFFFu);
    }
    for (int i = tid; i < nov; i += 256) {
        int2 p = ovp[i];
        if (p.y >= node_lo && p.y < node_hi) {
            int slot = atomicAdd(&lcur[p.y - node_lo], 1);
            lcsr[slot] = p.x;
        }
    }
    __syncthreads();
    for (int i = tid; i < cnt_total; i += 256) csr[bucket_base + i] = lcsr[i];
}

// layer 0: h = x[N,2] @ W[2,64]; per-head (4x16) alpha dots -> bf16 H.
__global__ __launch_bounds__(256) void k_feat0(const float* __restrict__ Xin,
                                               const float* __restrict__ W,
                                               const float* __restrict__ Asrc,
                                               const float* __restrict__ Adst,
                                               u16* __restrict__ Hb, float* __restrict__ asn,
                                               float* __restrict__ adn, int n) {
    const int wv = threadIdx.x >> 6, ln = threadIdx.x & 63;
    const float w0 = W[ln], w1 = W[64 + ln];
    const float a_s = Asrc[ln], a_d = Adst[ln];
    for (int node = blockIdx.x * 4 + wv; node < n; node += gridDim.x * 4) {
        float x0 = Xin[node * 2 + 0], x1 = Xin[node * 2 + 1];
        float acc = fmaf(x1, w1, x0 * w0);
        float ts = acc * a_s, td = acc * a_d;
        #pragma unroll
        for (int o = 1; o < 16; o <<= 1) {
            ts += __shfl_xor(ts, o, 16);
            td += __shfl_xor(td, o, 16);
        }
        Hb[node * 64 + ln] = f2bf(acc);
        if ((ln & 15) == 0) {
            asn[node * 4 + (ln >> 4)] = ts;
            adn[node * 4 + (ln >> 4)] = td;
        }
    }
}

// layer 1: h = X[N,64](f32) @ W[64,64] -> bf16 H + per-head alpha dots.
// Blocked-LDS: W staged once/block; wave does 4 nodes/iter, X transposed in
// wave-private LDS; per k: b32 W (conflict-free) + b128 broadcast + 4 FMA.
__global__ __launch_bounds__(256) void k_feat64(const float* __restrict__ Xin,
                                                const float* __restrict__ W,
                                                const float* __restrict__ Asrc,
                                                const float* __restrict__ Adst,
                                                u16* __restrict__ Hb, float* __restrict__ asn,
                                                float* __restrict__ adn, int n) {
    __shared__ float Ws[64 * 64];
    __shared__ __align__(16) float Xs[4][256];  // [wave][k*4 + nodeslot]
    for (int i = threadIdx.x; i < 64 * 64; i += 256) Ws[i] = W[i];
    __syncthreads();
    const int wv = threadIdx.x >> 6, ln = threadIdx.x & 63;
    const float a_s = Asrc[ln], a_d = Adst[ln];
    const int r = ln >> 4;
    const int c4 = (ln & 15) * 4;
    for (int g0 = blockIdx.x * 16 + wv * 4; g0 < n; g0 += gridDim.x * 16) {
        int node_r = g0 + r;
        float4 xq = (node_r < n) ? *(const float4*)&Xin[(size_t)node_r * 64 + c4]
                                 : make_float4(0.f, 0.f, 0.f, 0.f);
        Xs[wv][(c4 + 0) * 4 + r] = xq.x;
        Xs[wv][(c4 + 1) * 4 + r] = xq.y;
        Xs[wv][(c4 + 2) * 4 + r] = xq.z;
        Xs[wv][(c4 + 3) * 4 + r] = xq.w;
        float acc0 = 0.f, acc1 = 0.f, acc2 = 0.f, acc3 = 0.f;
        #pragma unroll 8
        for (int k = 0; k < 64; k++) {
            float w = Ws[k * 64 + ln];
            float4 xk = *(const float4*)&Xs[wv][k * 4];
            acc0 = fmaf(xk.x, w, acc0);
            acc1 = fmaf(xk.y, w, acc1);
            acc2 = fmaf(xk.z, w, acc2);
            acc3 = fmaf(xk.w, w, acc3);
        }
        #pragma unroll
        for (int j = 0; j < 4; j++) {
            int node = g0 + j;
            if (node >= n) break;
            float acc = (j == 0) ? acc0 : (j == 1) ? acc1 : (j == 2) ? acc2 : acc3;
            float ts = acc * a_s, td = acc * a_d;
            #pragma unroll
            for (int o = 1; o < 16; o <<= 1) {
                ts += __shfl_xor(ts, o, 16);
                td += __shfl_xor(td, o, 16);
            }
            Hb[(size_t)node * 64 + ln] = f2bf(acc);
            if ((ln & 15) == 0) {
                asn[node * 4 + (ln >> 4)] = ts;
                adn[node * 4 + (ln >> 4)] = td;
            }
        }
    }
}

// Fused segment softmax + aggregation, one wave per dst node, bf16 H gather.
// Upfront coalesced csr load (lane=edge) distributed via shfl with a
// WAVE-UNIFORM trip count; use predicated by group-uniform i<mainE. Spill
// loop (direct loads) for deg>64. NOTE: macro local is s_e (NOT s) to avoid
// shadowing the caller's variable (R14 bug: `int s = (s)` self-init).
#define EDGE_BODY(SRC)                                                        \
    {                                                                         \
        int s_e = (SRC);                                                      \
        float l = LRELU(asn[s_e * HEADS + head] + adme, 0.2f);                \
        float w = __expf(l);                                                  \
        sw += w;                                                              \
        uint4 hv = ((const uint4*)Hb)[s_e * 8 + q];                           \
        v2f w2 = {w, w};                                                      \
        v2f h;                                                                \
        h.x = __uint_as_float(hv.x << 16);                                    \
        h.y = __uint_as_float(hv.x & 0xffff0000u);                            \
        p0 += w2 * h;                                                         \
        h.x = __uint_as_float(hv.y << 16);                                    \
        h.y = __uint_as_float(hv.y & 0xffff0000u);                            \
        p1 += w2 * h;                                                         \
        h.x = __uint_as_float(hv.z << 16);                                    \
        h.y = __uint_as_float(hv.z & 0xffff0000u);                            \
        p2 += w2 * h;                                                         \
        h.x = __uint_as_float(hv.w << 16);                                    \
        h.y = __uint_as_float(hv.w & 0xffff0000u);                            \
        p3 += w2 * h;                                                         \
    }

template <int HEADS, int OUTMODE>
__global__ __launch_bounds__(256) void k_edge(const u16* __restrict__ Hb,
                                              const float* __restrict__ asn,
                                              const float* __restrict__ adn,
                                              const int* __restrict__ rowstart,
                                              const int* __restrict__ csr,
                                              const float* __restrict__ bias,
                                              float4* __restrict__ Outf,
                                              u16* __restrict__ Outb,
                                              const float* __restrict__ va,
                                              const float* __restrict__ vd,
                                              float* __restrict__ asn2,
                                              float* __restrict__ adn2, int n) {
    typedef float v2f __attribute__((ext_vector_type(2)));
    const int wv = threadIdx.x >> 6, ln = threadIdx.x & 63;
    const int node = blockIdx.x * 4 + wv;
    if (node >= n) return;
    const int g = ln >> 3, q = ln & 7;
    const int head = (HEADS == 4) ? (q >> 1) : 0;
    const int start = rowstart[node], end = rowstart[node + 1];
    const int deg = end - start;
    const float adme = adn[node * HEADS + head];

    // one coalesced load covers all edges of this node (deg<=64 path)
    int sload = (ln < deg) ? csr[start + ln] : 0;

    v2f p0 = {0.f, 0.f}, p1 = {0.f, 0.f}, p2 = {0.f, 0.f}, p3 = {0.f, 0.f};
    float sw = 0.f;
    const int mainE = deg < 64 ? deg : 64;
    const int T = (mainE + 7) >> 3;  // wave-uniform trip count
    for (int t = 0; t < T; t++) {
        int i = g + 8 * t;           // <= 63 always: valid, ACTIVE source lane
        int s = __shfl(sload, i);
        if (i < mainE) EDGE_BODY(s)  // group-uniform guard; no shadowing now
    }
    for (int eg = start + 64 + g; eg < end; eg += 8) EDGE_BODY(csr[eg])

    #pragma unroll
    for (int o = 8; o < 64; o <<= 1) {
        p0.x += __shfl_xor(p0.x, o); p0.y += __shfl_xor(p0.y, o);
        p1.x += __shfl_xor(p1.x, o); p1.y += __shfl_xor(p1.y, o);
        p2.x += __shfl_xor(p2.x, o); p2.y += __shfl_xor(p2.y, o);
        p3.x += __shfl_xor(p3.x, o); p3.y += __shfl_xor(p3.y, o);
        sw += __shfl_xor(sw, o);
    }
    if (ln < 8) {
        const float inv = 1.0f / sw;
        float r0 = p0.x * inv, r1 = p0.y * inv, r2 = p1.x * inv, r3 = p1.y * inv;
        float r4 = p2.x * inv, r5 = p2.y * inv, r6 = p3.x * inv, r7 = p3.y * inv;
        if constexpr (OUTMODE != 2) {
            const float4 bA = ((const float4*)bias)[2 * q];
            const float4 bB = ((const float4*)bias)[2 * q + 1];
            r0 = LRELU(r0 + bA.x, 0.01f); r1 = LRELU(r1 + bA.y, 0.01f);
            r2 = LRELU(r2 + bA.z, 0.01f); r3 = LRELU(r3 + bA.w, 0.01f);
            r4 = LRELU(r4 + bB.x, 0.01f); r5 = LRELU(r5 + bB.y, 0.01f);
            r6 = LRELU(r6 + bB.z, 0.01f); r7 = LRELU(r7 + bB.w, 0.01f);
        }
        if constexpr (OUTMODE == 1) {
            uint4 pb;
            pb.x = (u32)f2bf(r0) | ((u32)f2bf(r1) << 16);
            pb.y = (u32)f2bf(r2) | ((u32)f2bf(r3) << 16);
            pb.z = (u32)f2bf(r4) | ((u32)f2bf(r5) << 16);
            pb.w = (u32)f2bf(r6) | ((u32)f2bf(r7) << 16);
            ((uint4*)Outb)[node * 8 + q] = pb;
            // fused layer-2 alpha dots
            const float4 vA = ((const float4*)va)[2 * q];
            const float4 vB = ((const float4*)va)[2 * q + 1];
            const float4 dA = ((const float4*)vd)[2 * q];
            const float4 dB = ((const float4*)vd)[2 * q + 1];
            float ts = r0 * vA.x + r1 * vA.y + r2 * vA.z + r3 * vA.w +
                       r4 * vB.x + r5 * vB.y + r6 * vB.z + r7 * vB.w;
            float td = r0 * dA.x + r1 * dA.y + r2 * dA.z + r3 * dA.w +
                       r4 * dB.x + r5 * dB.y + r6 * dB.z + r7 * dB.w;
            ts += __shfl_xor(ts, 1, 8); td += __shfl_xor(td, 1, 8);
            ts += __shfl_xor(ts, 2, 8); td += __shfl_xor(td, 2, 8);
            ts += __shfl_xor(ts, 4, 8); td += __shfl_xor(td, 4, 8);
            if (ln == 0) { asn2[node] = ts; adn2[node] = td; }
        } else {
            float4 oA = make_float4(r0, r1, r2, r3);
            float4 oB = make_float4(r4, r5, r6, r7);
            Outf[node * 16 + 2 * q] = oA;
            Outf[node * 16 + 2 * q + 1] = oB;
        }
    }
}

// final dense: out = Agg[N,64] @ W2 + b2. Blocked-LDS like k_feat64.
__global__ __launch_bounds__(256) void k_out(const float* __restrict__ Agg,
                                             const float* __restrict__ W2,
                                             const float* __restrict__ b2,
                                             float* __restrict__ Out, int n) {
    __shared__ float Ws[64 * 64];
    __shared__ __align__(16) float Xs[4][256];
    for (int i = threadIdx.x; i < 64 * 64; i += 256) Ws[i] = W2[i];
    __syncthreads();
    const int wv = threadIdx.x >> 6, ln = threadIdx.x & 63;
    const float bb = b2[ln];
    const int r = ln >> 4;
    const int c4 = (ln & 15) * 4;
    for (int g0 = blockIdx.x * 16 + wv * 4; g0 < n; g0 += gridDim.x * 16) {
        int node_r = g0 + r;
        float4 xq = (node_r < n) ? *(const float4*)&Agg[(size_t)node_r * 64 + c4]
                                 : make_float4(0.f, 0.f, 0.f, 0.f);
        Xs[wv][(c4 + 0) * 4 + r] = xq.x;
        Xs[wv][(c4 + 1) * 4 + r] = xq.y;
        Xs[wv][(c4 + 2) * 4 + r] = xq.z;
        Xs[wv][(c4 + 3) * 4 + r] = xq.w;
        float acc0 = 0.f, acc1 = 0.f, acc2 = 0.f, acc3 = 0.f;
        #pragma unroll 8
        for (int k = 0; k < 64; k++) {
            float w = Ws[k * 64 + ln];
            float4 xk = *(const float4*)&Xs[wv][k * 4];
            acc0 = fmaf(xk.x, w, acc0);
            acc1 = fmaf(xk.y, w, acc1);
            acc2 = fmaf(xk.z, w, acc2);
            acc3 = fmaf(xk.w, w, acc3);
        }
        #pragma unroll
        for (int j = 0; j < 4; j++) {
            int node = g0 + j;
            if (node >= n) break;
            float acc = (j == 0) ? acc0 : (j == 1) ? acc1 : (j == 2) ? acc2 : acc3;
            Out[(size_t)node * 64 + ln] = acc + bb;
        }
    }
}

extern "C" void kernel_launch(void* const* d_in, const int* in_sizes, int n_in, void* d_out,
                              int out_size, void* d_ws, size_t ws_size, hipStream_t stream) {
    const float* x = (const float*)d_in[0];
    const int* eraw = (const int*)d_in[1];
    const float* W0 = (const float*)d_in[2];
    const float* as0 = (const float*)d_in[3];
    const float* ad0 = (const float*)d_in[4];
    const float* b0 = (const float*)d_in[5];
    const float* W1 = (const float*)d_in[6];
    const float* as1 = (const float*)d_in[7];
    const float* ad1 = (const float*)d_in[8];
    const float* b1 = (const float*)d_in[9];
    const float* W2 = (const float*)d_in[10];
    const float* as2 = (const float*)d_in[11];
    const float* ad2 = (const float*)d_in[12];
    const float* b2 = (const float*)d_in[13];

    const int n = in_sizes[0] / 2;   // x [N,2]
    const int e = in_sizes[1] / 2;   // edge_index [2,E]
    const int etot = e + n;

    char* wp = (char*)d_ws;
    size_t off = 0;
    auto take = [&](size_t bytes) -> void* {
        void* p = wp + off;
        off = (off + bytes + 255) & ~(size_t)255;
        return p;
    };
    // union: Hbf (bf16 N*64) + Xb2 (bf16 N*64) overlap keys (256*CAP_A*4)
    size_t hsz = (size_t)n * 64 * 2;
    size_t psz = (size_t)NBUCKET * CAP_A * 4;
    size_t usz = 2 * hsz > psz ? 2 * hsz : psz;
    char* ubase   = (char*)take(usz);
    u16* Hbf      = (u16*)ubase;
    u16* Xb2      = (u16*)(ubase + hsz);
    u32* keys     = (u32*)ubase;               // dead before Hbf/Xb2 are written
    float* asn    = (float*)take((size_t)n * 4 * 4);
    float* adn    = (float*)take((size_t)n * 4 * 4);
    float* asn2   = (float*)take((size_t)n * 4);
    float* adn2   = (float*)take((size_t)n * 4);
    int* rowstart = (int*)take((size_t)(n + 1) * 4);
    int* gcnt     = (int*)take(NBUCKET * 4);
    int* flag     = (int*)take(256);           // flag + ovcnt
    int* ovcnt    = flag + 1;
    float* va     = (float*)take(64 * 4);
    float* vd     = (float*)take(64 * 4);
    int2* ovp     = (int2*)take((size_t)OVCAP * 8);
    int* csr      = (int*)take((size_t)etot * 4);
    (void)ws_size;

    hipMemsetAsync(gcnt, 0, NBUCKET * 4, stream);
    hipMemsetAsync(flag, 0, 256, stream);

    k_init<<<1, 1024, 0, stream>>>(eraw, e, flag, W2, as2, ad2, va, vd);
    k_passA<<<(etot + ACHUNK - 1) / ACHUNK, 256, 0, stream>>>(eraw, e, etot, flag, n, keys,
                                                              gcnt, ovp, ovcnt);
    k_passB<<<NBUCKET, 256, 0, stream>>>(keys, gcnt, ovp, ovcnt, n, etot, rowstart, csr);

    const int nodeBlocks4 = (n + 3) / 4;
    const int gemmBlocks = 2048;
    float* Xact = (float*)d_out;  // f32 X1 activations, later Agg, finally output

    // layer 0
    k_feat0<<<nodeBlocks4, 256, 0, stream>>>(x, W0, as0, ad0, Hbf, asn, adn, n);
    k_edge<4, 0><<<nodeBlocks4, 256, 0, stream>>>(Hbf, asn, adn, rowstart, csr, b0,
                                                  (float4*)Xact, nullptr, nullptr, nullptr,
                                                  nullptr, nullptr, n);
    // layer 1 (k_edge also emits layer-2 alpha dots into asn2/adn2)
    k_feat64<<<gemmBlocks, 256, 0, stream>>>(Xact, W1, as1, ad1, Hbf, asn, adn, n);
    k_edge<4, 1><<<nodeBlocks4, 256, 0, stream>>>(Hbf, asn, adn, rowstart, csr, b1,
                                                  nullptr, Xb2, va, vd, asn2, adn2, n);
    // layer 2 (linearity): aggregate Xb2 -> Agg(d_out); dense in-place
    k_edge<1, 2><<<nodeBlocks4, 256, 0, stream>>>(Xb2, asn2, adn2, rowstart, csr, nullptr,
                                                  (float4*)Xact, nullptr, nullptr, nullptr,
                                                  nullptr, nullptr, n);
    k_out<<<gemmBlocks, 256, 0, stream>>>(Xact, W2, b2, (float*)d_out, n);
}